// Round 7
// baseline (543.667 us; speedup 1.0000x reference)
//
#include <hip/hip_runtime.h>
#include <math.h>

#define BB 32
#define LL 512
#define DD 512
#define NH 8
#define HD 64

typedef __attribute__((ext_vector_type(8))) short bf16x8;
typedef __attribute__((ext_vector_type(4))) float f32x4;

__device__ __forceinline__ unsigned short f2bf(float x) {
    union { float f; unsigned u; } v; v.f = x;
    unsigned r = v.u + 0x7fffu + ((v.u >> 16) & 1u);  // RNE
    return (unsigned short)(r >> 16);
}

// ---------------- reductions ----------------
__device__ __forceinline__ float warp_sum(float v) {
    #pragma unroll
    for (int o = 32; o > 0; o >>= 1) v += __shfl_down(v, o);
    return v;
}

// ---------------- LayerNorm: one block per row of 512, bf16 out ----------------
__global__ void ln_kernel(const float* __restrict__ X, const float* __restrict__ g,
                          const float* __restrict__ b, unsigned short* __restrict__ Y) {
    __shared__ float red[8];
    const size_t base = (size_t)blockIdx.x * DD;
    const int t = threadIdx.x;
    float x0 = X[base + t], x1 = X[base + t + 256];
    float s = warp_sum(x0 + x1);
    float q = warp_sum(x0 * x0 + x1 * x1);
    if ((t & 63) == 0) { red[t >> 6] = s; red[4 + (t >> 6)] = q; }
    __syncthreads();
    float S = red[0] + red[1] + red[2] + red[3];
    float Q = red[4] + red[5] + red[6] + red[7];
    float mu  = S * (1.0f / 512.0f);
    float var = Q * (1.0f / 512.0f) - mu * mu;
    float r = rsqrtf(var + 1e-5f);
    Y[base + t]       = f2bf((x0 - mu) * r * g[t] + b[t]);
    Y[base + t + 256] = f2bf((x1 - mu) * r * g[t + 256] + b[t + 256]);
}

// ---------------- weight transpose + bf16 cast: W (K x N) -> WT (N x K) ----------------
__global__ void transpose_bf16(const float* __restrict__ W, unsigned short* __restrict__ WT,
                               int K, int N) {
    __shared__ float t[32][33];
    const int n0 = blockIdx.x * 32, k0 = blockIdx.y * 32;
    const int tx = threadIdx.x & 31, ty = threadIdx.x >> 5;
    #pragma unroll
    for (int r = 0; r < 32; r += 8)
        t[ty + r][tx] = W[(size_t)(k0 + ty + r) * N + n0 + tx];
    __syncthreads();
    #pragma unroll
    for (int r = 0; r < 32; r += 8)
        WT[(size_t)(n0 + ty + r) * K + k0 + tx] = f2bf(t[tx][ty + r]);
}

// ---------------- bf16 MFMA GEMM, 2-phase double-buffered staging ----------------
// A: M x K bf16 row-major; BT: N x K bf16 row-major. 128x128 tile, BK=64.
// 2-phase (T3-minimal): two STATIC LDS buffer pairs, one barrier per K-step;
// stage of tile t+1 issued BEFORE compute(t), drains at the NEXT barrier.
// Grid 1D with XCD-bijective chunked swizzle (T1).
// OM: 0 = f32 out, 1 = bf16 out,
//     2 = qkv split: Q (x0.125 score-scale folded in) -> Cv row-major;
//         K -> kfrag blobs; V -> vfrag blobs.
template <int ACT, int RES, int OM>
__global__ __launch_bounds__(256)
void gemm_mfma(const unsigned short* __restrict__ A, const unsigned short* __restrict__ BT,
               const float* __restrict__ bias, const float* __restrict__ res,
               void* __restrict__ Cv, unsigned short* __restrict__ kfrag,
               unsigned short* __restrict__ vfrag, int M, int N, int K) {
    __shared__ unsigned short As0[128 * 64];
    __shared__ unsigned short Bs0[128 * 64];
    __shared__ unsigned short As1[128 * 64];
    __shared__ unsigned short Bs1[128 * 64];
    const int tid = threadIdx.x;
    const int wave = tid >> 6, lane = tid & 63;
    const int wm = (wave >> 1) * 64, wn = (wave & 1) * 64;

    // XCD-bijective chunked swizzle
    const int nx = N >> 7;
    const int chunk = (int)gridDim.x >> 3;
    const int o = ((int)blockIdx.x & 7) * chunk + ((int)blockIdx.x >> 3);
    const int bn = (o % nx) * 128;
    const int bm = (o / nx) * 128;

    f32x4 acc[4][4] = {};

    auto stage = [&](unsigned short* AS, unsigned short* BS, int k0) {
        #pragma unroll
        for (int it = 0; it < 4; ++it) {
            const int s = it * 256 + tid;
            const int row = s >> 3, pch = s & 7;
            const int lch = pch ^ (row & 7);
            const unsigned short* ga = A + (size_t)(bm + row) * K + k0 + lch * 8;
            __builtin_amdgcn_global_load_lds(
                (const __attribute__((address_space(1))) void*)ga,
                (__attribute__((address_space(3))) void*)(AS + s * 8), 16, 0, 0);
            const unsigned short* gb = BT + (size_t)(bn + row) * K + k0 + lch * 8;
            __builtin_amdgcn_global_load_lds(
                (const __attribute__((address_space(1))) void*)gb,
                (__attribute__((address_space(3))) void*)(BS + s * 8), 16, 0, 0);
        }
    };

    auto compute = [&](const unsigned short* AS, const unsigned short* BS) {
        #pragma unroll
        for (int ks = 0; ks < 2; ++ks) {
            bf16x8 af[4], bfr[4];
            #pragma unroll
            for (int i = 0; i < 4; ++i) {
                const int row = wm + i * 16 + (lane & 15);
                const int pch = (ks * 4 + (lane >> 4)) ^ (row & 7);
                af[i] = *(const bf16x8*)(AS + row * 64 + pch * 8);
            }
            #pragma unroll
            for (int j = 0; j < 4; ++j) {
                const int row = wn + j * 16 + (lane & 15);
                const int pch = (ks * 4 + (lane >> 4)) ^ (row & 7);
                bfr[j] = *(const bf16x8*)(BS + row * 64 + pch * 8);
            }
            #pragma unroll
            for (int i = 0; i < 4; ++i)
                #pragma unroll
                for (int j = 0; j < 4; ++j)
                    acc[i][j] = __builtin_amdgcn_mfma_f32_16x16x32_bf16(
                        af[i], bfr[j], acc[i][j], 0, 0, 0);
        }
    };

    stage(As0, Bs0, 0);
    for (int k0 = 0; k0 < K; k0 += 128) {
        __syncthreads();                             // drains stage of As0/Bs0
        if (k0 + 64 < K) stage(As1, Bs1, k0 + 64);   // flies under compute
        compute(As0, Bs0);
        __syncthreads();                             // drains stage of As1/Bs1
        if (k0 + 128 < K) stage(As0, Bs0, k0 + 128);
        compute(As1, Bs1);
    }

    const int cl = lane & 15, rq = (lane >> 4) * 4;
    #pragma unroll
    for (int j = 0; j < 4; ++j) {
        const int col = bn + wn + j * 16 + cl;
        const float bv = bias[col];
        #pragma unroll
        for (int i = 0; i < 4; ++i) {
            const int r0 = bm + wm + i * 16 + rq;
            #pragma unroll
            for (int r = 0; r < 4; ++r) {
                float v = acc[i][j][r] + bv;
                if (ACT == 1) v = 0.5f * v * (1.0f + erff(v * 0.70710678118654752f));
                if (RES) v += res[(size_t)(r0 + r) * N + col];
                if (OM == 0) {
                    ((float*)Cv)[(size_t)(r0 + r) * N + col] = v;
                } else if (OM == 1) {
                    ((unsigned short*)Cv)[(size_t)(r0 + r) * N + col] = f2bf(v);
                } else {
                    const int row = r0 + r;
                    const int b = row >> 9, kpos = row & 511;
                    if (col < 512) {
                        // Q: fold the 1/sqrt(HD)=0.125 score scale here (exact)
                        ((unsigned short*)Cv)[(size_t)row * 512 + col] = f2bf(v * 0.125f);
                    } else if (col < 1024) {
                        const int h = (col - 512) >> 6, dd = (col - 512) & 63;
                        const int kt = kpos >> 6, jj = (kpos >> 4) & 3, lo2 = kpos & 15;
                        const int kk = dd >> 5, hi2 = (dd >> 3) & 3, e = dd & 7;
                        kfrag[((((size_t)(b * NH + h) * 8 + kt) * 2 + kk) * 4 + jj) * 512
                              + (hi2 * 16 + lo2) * 8 + e] = f2bf(v);
                    } else {
                        const int h = (col - 1024) >> 6, dd = (col - 1024) & 63;
                        const int kt = kpos >> 6, kk = (kpos >> 5) & 1, hi2 = (kpos >> 3) & 3, e = kpos & 7;
                        const int jj = dd >> 4, lo2 = dd & 15;
                        vfrag[((((size_t)(b * NH + h) * 8 + kt) * 2 + kk) * 4 + jj) * 512
                              + (hi2 * 16 + lo2) * 8 + e] = f2bf(v);
                    }
                }
            }
        }
    }
}

// ---------------- fused flash attention v7: kf register rotation ----------------
// grid: (qg=32, b=32), 512 threads = 8 waves; wave w = head w.
// v7 changes vs v4 keeper:
//  - kf PREFETCH ROTATION, zero extra register sets: kf regs are dead right
//    after QK^T, so the loads for tile kt+1 are issued into the SAME kf regs
//    mid-iteration. The end-of-iter barrier's vmcnt(0) drain lands them
//    ~600+cy after issue -> next iteration's QK^T issues with NO vmcnt wait.
//    (v4 exposed full L2/L3 frag latency at every iteration start.)
//  - plds stride back to 72 (80 increased conflicts 5.77M->7.34M; conflicts
//    proven off the critical path, stop touching).
//  - score scale 0.125 folded into Q at the qkv GEMM -> bias chain is 4 FMA.
__global__ __launch_bounds__(512)
void flash_kernel(const unsigned short* __restrict__ qbuf,
                  const unsigned short* __restrict__ kfrag,
                  const unsigned short* __restrict__ vfrag,
                  const float* __restrict__ inter,
                  const float* __restrict__ iw,
                  unsigned short* __restrict__ O) {
    __shared__ float it[2][16 * 256];               // 2 x 16 KB inter tiles (linear)
    __shared__ unsigned short plds[8][16 * 72];     // per-wave P tile
    const int qg = blockIdx.x, b = blockIdx.y;
    const int tid = threadIdx.x, wave = tid >> 6, lane = tid & 63;
    const int h = wave;
    const int lo = lane & 15, hi = lane >> 4;

    const float iw0 = iw[h], iw1 = iw[8 + h], iw2 = iw[16 + h], iw3 = iw[24 + h];
    const float* interb = inter + (size_t)b * 512 * 512 * 4;
    unsigned short* pw = &plds[wave][0];

    // Q fragment (scaled by 0.125 at qkv GEMM): q-row = lo, d = kk*32 + hi*8 + e
    const unsigned short* qp = qbuf + ((size_t)(b * 512 + qg * 16 + lo)) * 512 + h * 64 + hi * 8;
    const bf16x8 qf0 = *(const bf16x8*)(qp);
    const bf16x8 qf1 = *(const bf16x8*)(qp + 32);

    // fragment blob bases (kt stride = 2*4*512 u16 = 4096)
    const unsigned short* kfb = kfrag + (size_t)(b * NH + h) * 32768 + (size_t)lane * 8;
    const unsigned short* vfb = vfrag + (size_t)(b * NH + h) * 32768 + (size_t)lane * 8;

    // staging: wave w stages tile rows {2w, 2w+1}; LDS dest linear,
    // global source chunk XOR-swizzled (lane ^ (row&7)).
    const int srow0 = wave * 2, srow1 = wave * 2 + 1;
    const float* sg0 = interb + (((size_t)(qg * 16 + srow0)) * 512 + (lane ^ (srow0 & 7))) * 4;
    const float* sg1 = interb + (((size_t)(qg * 16 + srow1)) * 512 + (lane ^ (srow1 & 7))) * 4;

    f32x4 o[4] = {};
    float m = -1e30f, lsum = 0.0f;

    // prologue: kf(0) into rotation regs + stage tile 0 into it[0]
    bf16x8 kf[8];
    #pragma unroll
    for (int jj = 0; jj < 8; ++jj)
        kf[jj] = *(const bf16x8*)(kfb + jj * 512);
    __builtin_amdgcn_global_load_lds(
        (const __attribute__((address_space(1))) void*)sg0,
        (__attribute__((address_space(3))) void*)(&it[0][srow0 * 256] + lane * 4), 16, 0, 0);
    __builtin_amdgcn_global_load_lds(
        (const __attribute__((address_space(1))) void*)sg1,
        (__attribute__((address_space(3))) void*)(&it[0][srow1 * 256] + lane * 4), 16, 0, 0);

    #pragma unroll 1
    for (int kt = 0; kt < 8; ++kt) {
        const int buf = kt & 1;
        __syncthreads();  // it[buf] + kf(kt) landed; it[buf^1] free to overwrite
        // (1) S^T = K Q^T immediately — kf already in regs, no vmem wait
        f32x4 s4[4] = {};
        __builtin_amdgcn_s_setprio(1);
        #pragma unroll
        for (int j = 0; j < 4; ++j)
            s4[j] = __builtin_amdgcn_mfma_f32_16x16x32_bf16(kf[j], qf0, s4[j], 0, 0, 0);
        #pragma unroll
        for (int j = 0; j < 4; ++j)
            s4[j] = __builtin_amdgcn_mfma_f32_16x16x32_bf16(kf[4 + j], qf1, s4[j], 0, 0, 0);
        __builtin_amdgcn_s_setprio(0);
        // (2) V fragments (oldest outstanding -> PV's wait leaves younger in flight)
        const unsigned short* vp = vfb + kt * 4096;
        bf16x8 vf[8];
        #pragma unroll
        for (int jj = 0; jj < 8; ++jj)
            vf[jj] = *(const bf16x8*)(vp + jj * 512);
        // (3) kf rotation: load tile kt+1 into the now-dead kf regs
        if (kt < 7) {
            const unsigned short* kp = kfb + (kt + 1) * 4096;
            #pragma unroll
            for (int jj = 0; jj < 8; ++jj)
                kf[jj] = *(const bf16x8*)(kp + jj * 512);
        }
        // (4) stage tile kt+1 (youngest; drains at next barrier)
        if (kt < 7) {
            const int kb2 = (kt + 1) * 64;
            __builtin_amdgcn_global_load_lds(
                (const __attribute__((address_space(1))) void*)(sg0 + kb2 * 4),
                (__attribute__((address_space(3))) void*)(&it[buf ^ 1][srow0 * 256] + lane * 4),
                16, 0, 0);
            __builtin_amdgcn_global_load_lds(
                (const __attribute__((address_space(1))) void*)(sg1 + kb2 * 4),
                (__attribute__((address_space(3))) void*)(&it[buf ^ 1][srow1 * 256] + lane * 4),
                16, 0, 0);
        }
        __builtin_amdgcn_sched_barrier(0);
        // (5) bias from LDS (swizzled read: chunk c stored at c^(lo&7)); Q pre-scaled
        {
            const float* bb = &it[buf][lo * 256];
            const int x7 = lo & 7;
            #pragma unroll
            for (int j = 0; j < 4; ++j) {
                #pragma unroll
                for (int r = 0; r < 4; ++r) {
                    const int c = (((hi * 4 + r) ^ x7) + j * 16) * 4;
                    const float4 f = *(const float4*)(bb + c);
                    s4[j][r] = s4[j][r] + f.x * iw0 + f.y * iw1 + f.z * iw2 + f.w * iw3;
                }
            }
        }
        // (6) online softmax, per-lane row q = lo (replicated over hi groups)
        float t0 = fmaxf(fmaxf(s4[0][0], s4[0][1]), fmaxf(s4[0][2], s4[0][3]));
        float t1 = fmaxf(fmaxf(s4[1][0], s4[1][1]), fmaxf(s4[1][2], s4[1][3]));
        float t2 = fmaxf(fmaxf(s4[2][0], s4[2][1]), fmaxf(s4[2][2], s4[2][3]));
        float t3 = fmaxf(fmaxf(s4[3][0], s4[3][1]), fmaxf(s4[3][2], s4[3][3]));
        float mx = fmaxf(fmaxf(t0, t1), fmaxf(t2, t3));
        mx = fmaxf(mx, __shfl_xor(mx, 16));
        mx = fmaxf(mx, __shfl_xor(mx, 32));
        const float mn = fmaxf(m, mx);
        const float al = __expf(m - mn);
        m = mn;
        #pragma unroll
        for (int j = 0; j < 4; ++j)
            #pragma unroll
            for (int r = 0; r < 4; ++r)
                s4[j][r] = __expf(s4[j][r] - mn);
        float u0 = (s4[0][0] + s4[0][1]) + (s4[0][2] + s4[0][3]);
        float u1 = (s4[1][0] + s4[1][1]) + (s4[1][2] + s4[1][3]);
        float u2 = (s4[2][0] + s4[2][1]) + (s4[2][2] + s4[2][3]);
        float u3 = (s4[3][0] + s4[3][1]) + (s4[3][2] + s4[3][3]);
        float ts = (u0 + u1) + (u2 + u3);
        ts += __shfl_xor(ts, 16);
        ts += __shfl_xor(ts, 32);
        lsum = lsum * al + ts;
        // (7) redistribute alpha to C-layout rows (q = hi*4 + r)
        const float aR0 = __shfl(al, hi * 4 + 0);
        const float aR1 = __shfl(al, hi * 4 + 1);
        const float aR2 = __shfl(al, hi * 4 + 2);
        const float aR3 = __shfl(al, hi * 4 + 3);
        #pragma unroll
        for (int j2 = 0; j2 < 4; ++j2) {
            o[j2][0] *= aR0; o[j2][1] *= aR1; o[j2][2] *= aR2; o[j2][3] *= aR3;
        }
        // (8) P -> LDS, packed b64, wave-private (no barrier needed)
        uint2* pq = (uint2*)(pw + lo * 72);
        #pragma unroll
        for (int j = 0; j < 4; ++j) {
            uint2 d;
            d.x = (unsigned)f2bf(s4[j][0]) | ((unsigned)f2bf(s4[j][1]) << 16);
            d.y = (unsigned)f2bf(s4[j][2]) | ((unsigned)f2bf(s4[j][3]) << 16);
            pq[j * 4 + hi] = d;
        }
        // (9) O += P V  (wait on vf leaves kf(kt+1) + stage in flight)
        __builtin_amdgcn_s_setprio(1);
        #pragma unroll
        for (int kk = 0; kk < 2; ++kk) {
            const bf16x8 pf = *(const bf16x8*)(pw + lo * 72 + kk * 32 + hi * 8);
            #pragma unroll
            for (int j2 = 0; j2 < 4; ++j2)
                o[j2] = __builtin_amdgcn_mfma_f32_16x16x32_bf16(
                    pf, vf[kk * 4 + j2], o[j2], 0, 0, 0);
        }
        __builtin_amdgcn_s_setprio(0);
    }

    // ---- epilogue ----
    const float iR0 = 1.0f / __shfl(lsum, hi * 4 + 0);
    const float iR1 = 1.0f / __shfl(lsum, hi * 4 + 1);
    const float iR2 = 1.0f / __shfl(lsum, hi * 4 + 2);
    const float iR3 = 1.0f / __shfl(lsum, hi * 4 + 3);
    const int qC0 = qg * 16 + hi * 4;
    #pragma unroll
    for (int j2 = 0; j2 < 4; ++j2) {
        O[(size_t)(b * 512 + qC0 + 0) * 512 + h * 64 + j2 * 16 + lo] = f2bf(o[j2][0] * iR0);
        O[(size_t)(b * 512 + qC0 + 1) * 512 + h * 64 + j2 * 16 + lo] = f2bf(o[j2][1] * iR1);
        O[(size_t)(b * 512 + qC0 + 2) * 512 + h * 64 + j2 * 16 + lo] = f2bf(o[j2][2] * iR2);
        O[(size_t)(b * 512 + qC0 + 3) * 512 + h * 64 + j2 * 16 + lo] = f2bf(o[j2][3] * iR3);
    }
}

// ---------------- launch ----------------
extern "C" void kernel_launch(void* const* d_in, const int* in_sizes, int n_in,
                              void* d_out, int out_size, void* d_ws, size_t ws_size,
                              hipStream_t stream) {
    const float* x     = (const float*)d_in[0];
    const float* inter = (const float*)d_in[1];
    const float* qkv_w = (const float*)d_in[2];
    const float* qkv_b = (const float*)d_in[3];
    const float* out_w = (const float*)d_in[4];
    const float* out_b = (const float*)d_in[5];
    const float* n1g   = (const float*)d_in[6];
    const float* n1b   = (const float*)d_in[7];
    const float* n2g   = (const float*)d_in[8];
    const float* n2b   = (const float*)d_in[9];
    const float* iw    = (const float*)d_in[10];
    const float* fw1   = (const float*)d_in[11];
    const float* fb1   = (const float*)d_in[12];
    const float* fw2   = (const float*)d_in[13];
    const float* fb2   = (const float*)d_in[14];
    float* out = (float*)d_out;

    // workspace layout (bytes): total 190,840,832
    //   qbuf    @ 0           : 16,777,216  (16384 x 512 bf16 Q, pre-scaled 0.125)
    //   kfrag   @ 16777216    : 16,777,216  (fragment blobs)
    //   vfrag   @ 33554432    : 16,777,216  (fragment blobs)
    //   attnout @ 50331648    : 16,777,216
    //   x2      @ 67108864    : 33,554,432  (fp32)
    //   h_bf    @ 100663296   : 16,777,216
    //   ffnmid  @ 117440512   : 67,108,864
    //   weights @ 184549376   : ~6.3 MB
    if (ws_size < 190840832ull) return;
    char* ws = (char*)d_ws;
    unsigned short* qbuf    = (unsigned short*)(ws);
    unsigned short* kfrag   = (unsigned short*)(ws + 16777216ull);
    unsigned short* vfrag   = (unsigned short*)(ws + 33554432ull);
    unsigned short* attnout = (unsigned short*)(ws + 50331648ull);
    float*          x2      = (float*)(ws + 67108864ull);
    unsigned short* h_bf    = (unsigned short*)(ws + 100663296ull);
    unsigned short* ffnmid  = (unsigned short*)(ws + 117440512ull);
    unsigned short* qkv_wT  = (unsigned short*)(ws + 184549376ull);
    unsigned short* out_wT  = (unsigned short*)(ws + 186122240ull);
    unsigned short* fw1T    = (unsigned short*)(ws + 186646528ull);
    unsigned short* fw2T    = (unsigned short*)(ws + 188743680ull);

    const int M = BB * LL;  // 16384

    // 0. weight transposes -> bf16 B^T
    transpose_bf16<<<dim3(1536 / 32, 512 / 32), 256, 0, stream>>>(qkv_w, qkv_wT, 512, 1536);
    transpose_bf16<<<dim3(512 / 32, 512 / 32), 256, 0, stream>>>(out_w, out_wT, 512, 512);
    transpose_bf16<<<dim3(2048 / 32, 512 / 32), 256, 0, stream>>>(fw1, fw1T, 512, 2048);
    transpose_bf16<<<dim3(512 / 32, 2048 / 32), 256, 0, stream>>>(fw2, fw2T, 2048, 512);
    // 1. LN1: x -> h_bf
    ln_kernel<<<M, 256, 0, stream>>>(x, n1g, n1b, h_bf);
    // 2. qkv GEMM -> qbuf + kfrag + vfrag (fragment-packed K/V); 1D swizzled grid
    gemm_mfma<0, 0, 2><<<dim3((1536 / 128) * (M / 128)), 256, 0, stream>>>(
        h_bf, qkv_wT, qkv_b, nullptr, qbuf, kfrag, vfrag, M, 1536, 512);
    // 3. fused flash attention (v7: kf rotation)
    flash_kernel<<<dim3(LL / 16, BB), 512, 0, stream>>>(qbuf, kfrag, vfrag, inter, iw, attnout);
    // 4. x2 = x + attnout @ out_w + out_b
    gemm_mfma<0, 1, 0><<<dim3((512 / 128) * (M / 128)), 256, 0, stream>>>(
        attnout, out_wT, out_b, x, x2, nullptr, nullptr, M, 512, 512);
    // 5. LN2: x2 -> h_bf
    ln_kernel<<<M, 256, 0, stream>>>(x2, n2g, n2b, h_bf);
    // 6. ffnmid = gelu(h2 @ fw1 + fb1) -> bf16
    gemm_mfma<1, 0, 1><<<dim3((2048 / 128) * (M / 128)), 256, 0, stream>>>(
        h_bf, fw1T, fb1, nullptr, ffnmid, nullptr, nullptr, M, 2048, 512);
    // 7. out = x2 + ffnmid @ fw2 + fb2
    gemm_mfma<0, 1, 0><<<dim3((512 / 128) * (M / 128)), 256, 0, stream>>>(
        ffnmid, fw2T, fb2, x2, out, nullptr, nullptr, M, 512, 2048);
}

// Round 8
// 534.961 us; speedup vs baseline: 1.0163x; 1.0163x over previous
//
#include <hip/hip_runtime.h>
#include <math.h>

#define BB 32
#define LL 512
#define DD 512
#define NH 8
#define HD 64

typedef __attribute__((ext_vector_type(8))) short bf16x8;
typedef __attribute__((ext_vector_type(4))) float f32x4;

__device__ __forceinline__ unsigned short f2bf(float x) {
    union { float f; unsigned u; } v; v.f = x;
    unsigned r = v.u + 0x7fffu + ((v.u >> 16) & 1u);  // RNE
    return (unsigned short)(r >> 16);
}

// ---------------- reductions ----------------
__device__ __forceinline__ float warp_sum(float v) {
    #pragma unroll
    for (int o = 32; o > 0; o >>= 1) v += __shfl_down(v, o);
    return v;
}

// ---------------- LayerNorm: one block per row of 512, bf16 out ----------------
__global__ void ln_kernel(const float* __restrict__ X, const float* __restrict__ g,
                          const float* __restrict__ b, unsigned short* __restrict__ Y) {
    __shared__ float red[8];
    const size_t base = (size_t)blockIdx.x * DD;
    const int t = threadIdx.x;
    float x0 = X[base + t], x1 = X[base + t + 256];
    float s = warp_sum(x0 + x1);
    float q = warp_sum(x0 * x0 + x1 * x1);
    if ((t & 63) == 0) { red[t >> 6] = s; red[4 + (t >> 6)] = q; }
    __syncthreads();
    float S = red[0] + red[1] + red[2] + red[3];
    float Q = red[4] + red[5] + red[6] + red[7];
    float mu  = S * (1.0f / 512.0f);
    float var = Q * (1.0f / 512.0f) - mu * mu;
    float r = rsqrtf(var + 1e-5f);
    Y[base + t]       = f2bf((x0 - mu) * r * g[t] + b[t]);
    Y[base + t + 256] = f2bf((x1 - mu) * r * g[t + 256] + b[t + 256]);
}

// ---------------- weight transpose + bf16 cast: W (K x N) -> WT (N x K) ----------------
__global__ void transpose_bf16(const float* __restrict__ W, unsigned short* __restrict__ WT,
                               int K, int N) {
    __shared__ float t[32][33];
    const int n0 = blockIdx.x * 32, k0 = blockIdx.y * 32;
    const int tx = threadIdx.x & 31, ty = threadIdx.x >> 5;
    #pragma unroll
    for (int r = 0; r < 32; r += 8)
        t[ty + r][tx] = W[(size_t)(k0 + ty + r) * N + n0 + tx];
    __syncthreads();
    #pragma unroll
    for (int r = 0; r < 32; r += 8)
        WT[(size_t)(n0 + ty + r) * K + k0 + tx] = f2bf(t[tx][ty + r]);
}

// ---------------- shared epilogue element-store (global row/col based) ----------------
// OM: 0 = f32 out, 1 = bf16 out,
//     2 = qkv split: Q (x0.125 folded) -> row-major [row][512]; K/V -> frag blobs.
template <int ACT, int RES, int OM>
__device__ __forceinline__ void epi_store(
    float v, int row, int col, int N,
    const float* __restrict__ res, void* __restrict__ Cv,
    unsigned short* __restrict__ kfrag, unsigned short* __restrict__ vfrag) {
    if (ACT == 1) v = 0.5f * v * (1.0f + erff(v * 0.70710678118654752f));
    if (RES) v += res[(size_t)row * N + col];
    if (OM == 0) {
        ((float*)Cv)[(size_t)row * N + col] = v;
    } else if (OM == 1) {
        ((unsigned short*)Cv)[(size_t)row * N + col] = f2bf(v);
    } else {
        const int b = row >> 9, kpos = row & 511;
        if (col < 512) {
            // Q: fold the 1/sqrt(HD)=0.125 score scale here (exact, exponent-only)
            ((unsigned short*)Cv)[(size_t)row * 512 + col] = f2bf(v * 0.125f);
        } else if (col < 1024) {
            const int h = (col - 512) >> 6, dd = (col - 512) & 63;
            const int kt = kpos >> 6, jj = (kpos >> 4) & 3, lo2 = kpos & 15;
            const int kk = dd >> 5, hi2 = (dd >> 3) & 3, e = dd & 7;
            kfrag[((((size_t)(b * NH + h) * 8 + kt) * 2 + kk) * 4 + jj) * 512
                  + (hi2 * 16 + lo2) * 8 + e] = f2bf(v);
        } else {
            const int h = (col - 1024) >> 6, dd = (col - 1024) & 63;
            const int kt = kpos >> 6, kk = (kpos >> 5) & 1, hi2 = (kpos >> 3) & 3, e = kpos & 7;
            const int jj = dd >> 4, lo2 = dd & 15;
            vfrag[((((size_t)(b * NH + h) * 8 + kt) * 2 + kk) * 4 + jj) * 512
                  + (hi2 * 16 + lo2) * 8 + e] = f2bf(v);
        }
    }
}

// ---------------- bf16 MFMA GEMM, 128x128 tile, 2-phase staging ----------------
// Used for N=512 GEMMs (attnout, ffn2): grid 512 blocks = 2/CU.
template <int ACT, int RES, int OM>
__global__ __launch_bounds__(256)
void gemm_mfma(const unsigned short* __restrict__ A, const unsigned short* __restrict__ BT,
               const float* __restrict__ bias, const float* __restrict__ res,
               void* __restrict__ Cv, unsigned short* __restrict__ kfrag,
               unsigned short* __restrict__ vfrag, int M, int N, int K) {
    __shared__ unsigned short As0[128 * 64];
    __shared__ unsigned short Bs0[128 * 64];
    __shared__ unsigned short As1[128 * 64];
    __shared__ unsigned short Bs1[128 * 64];
    const int tid = threadIdx.x;
    const int wave = tid >> 6, lane = tid & 63;
    const int wm = (wave >> 1) * 64, wn = (wave & 1) * 64;

    // XCD-bijective chunked swizzle (T1)
    const int nx = N >> 7;
    const int chunk = (int)gridDim.x >> 3;
    const int o = ((int)blockIdx.x & 7) * chunk + ((int)blockIdx.x >> 3);
    const int bn = (o % nx) * 128;
    const int bm = (o / nx) * 128;

    f32x4 acc[4][4] = {};

    auto stage = [&](unsigned short* AS, unsigned short* BS, int k0) {
        #pragma unroll
        for (int it = 0; it < 4; ++it) {
            const int s = it * 256 + tid;
            const int row = s >> 3, pch = s & 7;
            const int lch = pch ^ (row & 7);
            const unsigned short* ga = A + (size_t)(bm + row) * K + k0 + lch * 8;
            __builtin_amdgcn_global_load_lds(
                (const __attribute__((address_space(1))) void*)ga,
                (__attribute__((address_space(3))) void*)(AS + s * 8), 16, 0, 0);
            const unsigned short* gb = BT + (size_t)(bn + row) * K + k0 + lch * 8;
            __builtin_amdgcn_global_load_lds(
                (const __attribute__((address_space(1))) void*)gb,
                (__attribute__((address_space(3))) void*)(BS + s * 8), 16, 0, 0);
        }
    };

    auto compute = [&](const unsigned short* AS, const unsigned short* BS) {
        #pragma unroll
        for (int ks = 0; ks < 2; ++ks) {
            bf16x8 af[4], bfr[4];
            #pragma unroll
            for (int i = 0; i < 4; ++i) {
                const int row = wm + i * 16 + (lane & 15);
                const int pch = (ks * 4 + (lane >> 4)) ^ (row & 7);
                af[i] = *(const bf16x8*)(AS + row * 64 + pch * 8);
            }
            #pragma unroll
            for (int j = 0; j < 4; ++j) {
                const int row = wn + j * 16 + (lane & 15);
                const int pch = (ks * 4 + (lane >> 4)) ^ (row & 7);
                bfr[j] = *(const bf16x8*)(BS + row * 64 + pch * 8);
            }
            #pragma unroll
            for (int i = 0; i < 4; ++i)
                #pragma unroll
                for (int j = 0; j < 4; ++j)
                    acc[i][j] = __builtin_amdgcn_mfma_f32_16x16x32_bf16(
                        af[i], bfr[j], acc[i][j], 0, 0, 0);
        }
    };

    stage(As0, Bs0, 0);
    for (int k0 = 0; k0 < K; k0 += 128) {
        __syncthreads();
        if (k0 + 64 < K) stage(As1, Bs1, k0 + 64);
        compute(As0, Bs0);
        __syncthreads();
        if (k0 + 128 < K) stage(As0, Bs0, k0 + 128);
        compute(As1, Bs1);
    }

    const int cl = lane & 15, rq = (lane >> 4) * 4;
    #pragma unroll
    for (int j = 0; j < 4; ++j) {
        const int col = bn + wn + j * 16 + cl;
        const float bv = bias[col];
        #pragma unroll
        for (int i = 0; i < 4; ++i) {
            const int r0 = bm + wm + i * 16 + rq;
            #pragma unroll
            for (int r = 0; r < 4; ++r)
                epi_store<ACT, RES, OM>(acc[i][j][r] + bv, r0 + r, col, N, res, Cv, kfrag, vfrag);
        }
    }
}

// ---------------- bf16 MFMA GEMM, 256x256 tile, 8 waves, 2-phase ----------------
// For the fat GEMMs (qkv N=1536 grid 384; ffn1 N=2048 grid 512).
// Wave tile 128x64 (2M x 4N waves): ds_read per MFMA 0.375 (vs 0.5 at 64x64)
// and half the blocks -> better prologue/epilogue amortization at K=512's
// short 8-step loop. m230-V0 structure class (682 TF measured vs 622 for
// 128², both 2-phase). LDS 128 KB (4 static buffers) -> 1 block/CU, 8 waves.
// acc[8][4] = 128 VGPR; launch_bounds(512,2) caps at 256 -> no spill expected.
template <int ACT, int OM>
__global__ __launch_bounds__(512, 2)
void gemm_mfma256(const unsigned short* __restrict__ A, const unsigned short* __restrict__ BT,
                  const float* __restrict__ bias, void* __restrict__ Cv,
                  unsigned short* __restrict__ kfrag, unsigned short* __restrict__ vfrag,
                  int M, int N, int K) {
    __shared__ unsigned short As0[256 * 64];
    __shared__ unsigned short Bs0[256 * 64];
    __shared__ unsigned short As1[256 * 64];
    __shared__ unsigned short Bs1[256 * 64];
    const int tid = threadIdx.x;
    const int wave = tid >> 6, lane = tid & 63;
    const int wm = (wave >> 2) * 128, wn = (wave & 3) * 64;

    // XCD-bijective chunked swizzle (grids 384/512, both %8==0)
    const int nx = N >> 8;
    const int chunk = (int)gridDim.x >> 3;
    const int o = ((int)blockIdx.x & 7) * chunk + ((int)blockIdx.x >> 3);
    const int bn = (o % nx) * 256;
    const int bm = (o / nx) * 256;

    f32x4 acc[8][4] = {};

    auto stage = [&](unsigned short* AS, unsigned short* BS, int k0) {
        #pragma unroll
        for (int it = 0; it < 4; ++it) {
            const int s = it * 512 + tid;            // 2048 slots = 256 rows x 8 chunks
            const int row = s >> 3, pch = s & 7;
            const int lch = pch ^ (row & 7);
            const unsigned short* ga = A + (size_t)(bm + row) * K + k0 + lch * 8;
            __builtin_amdgcn_global_load_lds(
                (const __attribute__((address_space(1))) void*)ga,
                (__attribute__((address_space(3))) void*)(AS + s * 8), 16, 0, 0);
            const unsigned short* gb = BT + (size_t)(bn + row) * K + k0 + lch * 8;
            __builtin_amdgcn_global_load_lds(
                (const __attribute__((address_space(1))) void*)gb,
                (__attribute__((address_space(3))) void*)(BS + s * 8), 16, 0, 0);
        }
    };

    auto compute = [&](const unsigned short* AS, const unsigned short* BS) {
        #pragma unroll
        for (int ks = 0; ks < 2; ++ks) {
            bf16x8 bfr[4];
            #pragma unroll
            for (int j = 0; j < 4; ++j) {
                const int row = wn + j * 16 + (lane & 15);
                const int pch = (ks * 4 + (lane >> 4)) ^ (row & 7);
                bfr[j] = *(const bf16x8*)(BS + row * 64 + pch * 8);
            }
            bf16x8 af[8];
            #pragma unroll
            for (int i = 0; i < 8; ++i) {
                const int row = wm + i * 16 + (lane & 15);
                const int pch = (ks * 4 + (lane >> 4)) ^ (row & 7);
                af[i] = *(const bf16x8*)(AS + row * 64 + pch * 8);
            }
            #pragma unroll
            for (int i = 0; i < 8; ++i)
                #pragma unroll
                for (int j = 0; j < 4; ++j)
                    acc[i][j] = __builtin_amdgcn_mfma_f32_16x16x32_bf16(
                        af[i], bfr[j], acc[i][j], 0, 0, 0);
        }
    };

    stage(As0, Bs0, 0);
    for (int k0 = 0; k0 < K; k0 += 128) {
        __syncthreads();
        if (k0 + 64 < K) stage(As1, Bs1, k0 + 64);
        compute(As0, Bs0);
        __syncthreads();
        if (k0 + 128 < K) stage(As0, Bs0, k0 + 128);
        compute(As1, Bs1);
    }

    const int cl = lane & 15, rq = (lane >> 4) * 4;
    #pragma unroll
    for (int j = 0; j < 4; ++j) {
        const int col = bn + wn + j * 16 + cl;
        const float bv = bias[col];
        #pragma unroll
        for (int i = 0; i < 8; ++i) {
            const int r0 = bm + wm + i * 16 + rq;
            #pragma unroll
            for (int r = 0; r < 4; ++r)
                epi_store<ACT, 0, OM>(acc[i][j][r] + bv, r0 + r, col, N, nullptr, Cv, kfrag, vfrag);
        }
    }
}

// ---------------- fused flash attention (v4 keeper, reverted from v7) ----------------
// grid: (qg=32, b=32), 512 threads = 8 waves; wave w = head w.
// Schedule: barrier -> kf -> vf -> stage(kt+1) -> QK^T -> bias -> softmax ->
// P-LDS -> PV. kf-rotation (R7) REVERTED: it raised VGPR 64->84, occupancy
// 38->23%, flash 102->127. Flash lives at VGPR <= 64; TLP > prefetch here.
// Q is pre-scaled by 0.125 at the qkv GEMM -> bias chain has no extra mul.
__global__ __launch_bounds__(512)
void flash_kernel(const unsigned short* __restrict__ qbuf,
                  const unsigned short* __restrict__ kfrag,
                  const unsigned short* __restrict__ vfrag,
                  const float* __restrict__ inter,
                  const float* __restrict__ iw,
                  unsigned short* __restrict__ O) {
    __shared__ float it[2][16 * 256];               // 2 x 16 KB inter tiles (linear)
    __shared__ unsigned short plds[8][16 * 72];     // per-wave P tile
    const int qg = blockIdx.x, b = blockIdx.y;
    const int tid = threadIdx.x, wave = tid >> 6, lane = tid & 63;
    const int h = wave;
    const int lo = lane & 15, hi = lane >> 4;

    const float iw0 = iw[h], iw1 = iw[8 + h], iw2 = iw[16 + h], iw3 = iw[24 + h];
    const float* interb = inter + (size_t)b * 512 * 512 * 4;
    unsigned short* pw = &plds[wave][0];

    // Q fragment (pre-scaled 0.125): q-row = lo, d = kk*32 + hi*8 + e
    const unsigned short* qp = qbuf + ((size_t)(b * 512 + qg * 16 + lo)) * 512 + h * 64 + hi * 8;
    const bf16x8 qf0 = *(const bf16x8*)(qp);
    const bf16x8 qf1 = *(const bf16x8*)(qp + 32);

    // fragment blob bases (kt stride = 2*4*512 u16 = 4096)
    const unsigned short* kfb = kfrag + (size_t)(b * NH + h) * 32768 + (size_t)lane * 8;
    const unsigned short* vfb = vfrag + (size_t)(b * NH + h) * 32768 + (size_t)lane * 8;

    // staging: wave w stages tile rows {2w, 2w+1}; LDS dest linear,
    // global source chunk XOR-swizzled (lane ^ (row&7)).
    const int srow0 = wave * 2, srow1 = wave * 2 + 1;
    const float* sg0 = interb + (((size_t)(qg * 16 + srow0)) * 512 + (lane ^ (srow0 & 7))) * 4;
    const float* sg1 = interb + (((size_t)(qg * 16 + srow1)) * 512 + (lane ^ (srow1 & 7))) * 4;

    f32x4 o[4] = {};
    float m = -1e30f, lsum = 0.0f;

    // prologue: stage tile 0 into it[0]
    __builtin_amdgcn_global_load_lds(
        (const __attribute__((address_space(1))) void*)sg0,
        (__attribute__((address_space(3))) void*)(&it[0][srow0 * 256] + lane * 4), 16, 0, 0);
    __builtin_amdgcn_global_load_lds(
        (const __attribute__((address_space(1))) void*)sg1,
        (__attribute__((address_space(3))) void*)(&it[0][srow1 * 256] + lane * 4), 16, 0, 0);

    #pragma unroll 1
    for (int kt = 0; kt < 8; ++kt) {
        const int buf = kt & 1;
        __syncthreads();  // it[buf] staged & visible; it[buf^1] free to overwrite
        // (1) K fragments (oldest in vmcnt queue -> counted wait at QK^T)
        const unsigned short* kp = kfb + kt * 4096;
        bf16x8 kf[8];
        #pragma unroll
        for (int jj = 0; jj < 8; ++jj)
            kf[jj] = *(const bf16x8*)(kp + jj * 512);
        // (2) V fragments (consumed at PV; older than stage so PV's wait
        //     never forces the HBM stage to complete)
        const unsigned short* vp = vfb + kt * 4096;
        bf16x8 vf[8];
        #pragma unroll
        for (int jj = 0; jj < 8; ++jj)
            vf[jj] = *(const bf16x8*)(vp + jj * 512);
        // (3) stage tile kt+1 (youngest; drains at next barrier)
        if (kt < 7) {
            const int kb2 = (kt + 1) * 64;
            __builtin_amdgcn_global_load_lds(
                (const __attribute__((address_space(1))) void*)(sg0 + kb2 * 4),
                (__attribute__((address_space(3))) void*)(&it[buf ^ 1][srow0 * 256] + lane * 4),
                16, 0, 0);
            __builtin_amdgcn_global_load_lds(
                (const __attribute__((address_space(1))) void*)(sg1 + kb2 * 4),
                (__attribute__((address_space(3))) void*)(&it[buf ^ 1][srow1 * 256] + lane * 4),
                16, 0, 0);
        }
        __builtin_amdgcn_sched_barrier(0);
        // (4) S^T = K Q^T : lane owns q = lo, k = j*16 + hi*4 + r
        f32x4 s4[4] = {};
        __builtin_amdgcn_s_setprio(1);
        #pragma unroll
        for (int j = 0; j < 4; ++j)
            s4[j] = __builtin_amdgcn_mfma_f32_16x16x32_bf16(kf[j], qf0, s4[j], 0, 0, 0);
        #pragma unroll
        for (int j = 0; j < 4; ++j)
            s4[j] = __builtin_amdgcn_mfma_f32_16x16x32_bf16(kf[4 + j], qf1, s4[j], 0, 0, 0);
        __builtin_amdgcn_s_setprio(0);
        // (5) bias from LDS (swizzled read: chunk c stored at c^(lo&7)); Q pre-scaled
        {
            const float* bb = &it[buf][lo * 256];
            const int x7 = lo & 7;
            #pragma unroll
            for (int j = 0; j < 4; ++j) {
                #pragma unroll
                for (int r = 0; r < 4; ++r) {
                    const int c = (((hi * 4 + r) ^ x7) + j * 16) * 4;
                    const float4 f = *(const float4*)(bb + c);
                    s4[j][r] = s4[j][r] + f.x * iw0 + f.y * iw1 + f.z * iw2 + f.w * iw3;
                }
            }
        }
        // (6) online softmax, per-lane row q = lo (replicated over hi groups)
        float t0 = fmaxf(fmaxf(s4[0][0], s4[0][1]), fmaxf(s4[0][2], s4[0][3]));
        float t1 = fmaxf(fmaxf(s4[1][0], s4[1][1]), fmaxf(s4[1][2], s4[1][3]));
        float t2 = fmaxf(fmaxf(s4[2][0], s4[2][1]), fmaxf(s4[2][2], s4[2][3]));
        float t3 = fmaxf(fmaxf(s4[3][0], s4[3][1]), fmaxf(s4[3][2], s4[3][3]));
        float mx = fmaxf(fmaxf(t0, t1), fmaxf(t2, t3));
        mx = fmaxf(mx, __shfl_xor(mx, 16));
        mx = fmaxf(mx, __shfl_xor(mx, 32));
        const float mn = fmaxf(m, mx);
        const float al = __expf(m - mn);
        m = mn;
        #pragma unroll
        for (int j = 0; j < 4; ++j)
            #pragma unroll
            for (int r = 0; r < 4; ++r)
                s4[j][r] = __expf(s4[j][r] - mn);
        float u0 = (s4[0][0] + s4[0][1]) + (s4[0][2] + s4[0][3]);
        float u1 = (s4[1][0] + s4[1][1]) + (s4[1][2] + s4[1][3]);
        float u2 = (s4[2][0] + s4[2][1]) + (s4[2][2] + s4[2][3]);
        float u3 = (s4[3][0] + s4[3][1]) + (s4[3][2] + s4[3][3]);
        float ts = (u0 + u1) + (u2 + u3);
        ts += __shfl_xor(ts, 16);
        ts += __shfl_xor(ts, 32);
        lsum = lsum * al + ts;
        // (7) redistribute alpha to C-layout rows (q = hi*4 + r)
        const float aR0 = __shfl(al, hi * 4 + 0);
        const float aR1 = __shfl(al, hi * 4 + 1);
        const float aR2 = __shfl(al, hi * 4 + 2);
        const float aR3 = __shfl(al, hi * 4 + 3);
        #pragma unroll
        for (int j2 = 0; j2 < 4; ++j2) {
            o[j2][0] *= aR0; o[j2][1] *= aR1; o[j2][2] *= aR2; o[j2][3] *= aR3;
        }
        // (8) P -> LDS, packed b64, wave-private (no barrier needed)
        uint2* pq = (uint2*)(pw + lo * 72);
        #pragma unroll
        for (int j = 0; j < 4; ++j) {
            uint2 d;
            d.x = (unsigned)f2bf(s4[j][0]) | ((unsigned)f2bf(s4[j][1]) << 16);
            d.y = (unsigned)f2bf(s4[j][2]) | ((unsigned)f2bf(s4[j][3]) << 16);
            pq[j * 4 + hi] = d;
        }
        // (9) O += P V
        __builtin_amdgcn_s_setprio(1);
        #pragma unroll
        for (int kk = 0; kk < 2; ++kk) {
            const bf16x8 pf = *(const bf16x8*)(pw + lo * 72 + kk * 32 + hi * 8);
            #pragma unroll
            for (int j2 = 0; j2 < 4; ++j2)
                o[j2] = __builtin_amdgcn_mfma_f32_16x16x32_bf16(
                    pf, vf[kk * 4 + j2], o[j2], 0, 0, 0);
        }
        __builtin_amdgcn_s_setprio(0);
    }

    // ---- epilogue ----
    const float iR0 = 1.0f / __shfl(lsum, hi * 4 + 0);
    const float iR1 = 1.0f / __shfl(lsum, hi * 4 + 1);
    const float iR2 = 1.0f / __shfl(lsum, hi * 4 + 2);
    const float iR3 = 1.0f / __shfl(lsum, hi * 4 + 3);
    const int qC0 = qg * 16 + hi * 4;
    #pragma unroll
    for (int j2 = 0; j2 < 4; ++j2) {
        O[(size_t)(b * 512 + qC0 + 0) * 512 + h * 64 + j2 * 16 + lo] = f2bf(o[j2][0] * iR0);
        O[(size_t)(b * 512 + qC0 + 1) * 512 + h * 64 + j2 * 16 + lo] = f2bf(o[j2][1] * iR1);
        O[(size_t)(b * 512 + qC0 + 2) * 512 + h * 64 + j2 * 16 + lo] = f2bf(o[j2][2] * iR2);
        O[(size_t)(b * 512 + qC0 + 3) * 512 + h * 64 + j2 * 16 + lo] = f2bf(o[j2][3] * iR3);
    }
}

// ---------------- launch ----------------
extern "C" void kernel_launch(void* const* d_in, const int* in_sizes, int n_in,
                              void* d_out, int out_size, void* d_ws, size_t ws_size,
                              hipStream_t stream) {
    const float* x     = (const float*)d_in[0];
    const float* inter = (const float*)d_in[1];
    const float* qkv_w = (const float*)d_in[2];
    const float* qkv_b = (const float*)d_in[3];
    const float* out_w = (const float*)d_in[4];
    const float* out_b = (const float*)d_in[5];
    const float* n1g   = (const float*)d_in[6];
    const float* n1b   = (const float*)d_in[7];
    const float* n2g   = (const float*)d_in[8];
    const float* n2b   = (const float*)d_in[9];
    const float* iw    = (const float*)d_in[10];
    const float* fw1   = (const float*)d_in[11];
    const float* fb1   = (const float*)d_in[12];
    const float* fw2   = (const float*)d_in[13];
    const float* fb2   = (const float*)d_in[14];
    float* out = (float*)d_out;

    // workspace layout (bytes): total 190,840,832
    //   qbuf    @ 0           : 16,777,216  (16384 x 512 bf16 Q, pre-scaled 0.125)
    //   kfrag   @ 16777216    : 16,777,216  (fragment blobs)
    //   vfrag   @ 33554432    : 16,777,216  (fragment blobs)
    //   attnout @ 50331648    : 16,777,216
    //   x2      @ 67108864    : 33,554,432  (fp32)
    //   h_bf    @ 100663296   : 16,777,216
    //   ffnmid  @ 117440512   : 67,108,864
    //   weights @ 184549376   : ~6.3 MB
    if (ws_size < 190840832ull) return;
    char* ws = (char*)d_ws;
    unsigned short* qbuf    = (unsigned short*)(ws);
    unsigned short* kfrag   = (unsigned short*)(ws + 16777216ull);
    unsigned short* vfrag   = (unsigned short*)(ws + 33554432ull);
    unsigned short* attnout = (unsigned short*)(ws + 50331648ull);
    float*          x2      = (float*)(ws + 67108864ull);
    unsigned short* h_bf    = (unsigned short*)(ws + 100663296ull);
    unsigned short* ffnmid  = (unsigned short*)(ws + 117440512ull);
    unsigned short* qkv_wT  = (unsigned short*)(ws + 184549376ull);
    unsigned short* out_wT  = (unsigned short*)(ws + 186122240ull);
    unsigned short* fw1T    = (unsigned short*)(ws + 186646528ull);
    unsigned short* fw2T    = (unsigned short*)(ws + 188743680ull);

    const int M = BB * LL;  // 16384

    // 0. weight transposes -> bf16 B^T
    transpose_bf16<<<dim3(1536 / 32, 512 / 32), 256, 0, stream>>>(qkv_w, qkv_wT, 512, 1536);
    transpose_bf16<<<dim3(512 / 32, 512 / 32), 256, 0, stream>>>(out_w, out_wT, 512, 512);
    transpose_bf16<<<dim3(2048 / 32, 512 / 32), 256, 0, stream>>>(fw1, fw1T, 512, 2048);
    transpose_bf16<<<dim3(512 / 32, 2048 / 32), 256, 0, stream>>>(fw2, fw2T, 2048, 512);
    // 1. LN1: x -> h_bf
    ln_kernel<<<M, 256, 0, stream>>>(x, n1g, n1b, h_bf);
    // 2. qkv GEMM (256² tile) -> qbuf + kfrag + vfrag; grid 6*64=384 (%8==0)
    gemm_mfma256<0, 2><<<dim3((1536 / 256) * (M / 256)), 512, 0, stream>>>(
        h_bf, qkv_wT, qkv_b, qbuf, kfrag, vfrag, M, 1536, 512);
    // 3. fused flash attention (v4 keeper)
    flash_kernel<<<dim3(LL / 16, BB), 512, 0, stream>>>(qbuf, kfrag, vfrag, inter, iw, attnout);
    // 4. x2 = x + attnout @ out_w + out_b (128² tile, N=512)
    gemm_mfma<0, 1, 0><<<dim3((512 / 128) * (M / 128)), 256, 0, stream>>>(
        attnout, out_wT, out_b, x, x2, nullptr, nullptr, M, 512, 512);
    // 5. LN2: x2 -> h_bf
    ln_kernel<<<M, 256, 0, stream>>>(x2, n2g, n2b, h_bf);
    // 6. ffnmid = gelu(h2 @ fw1 + fb1) -> bf16 (256² tile); grid 8*64=512
    gemm_mfma256<1, 1><<<dim3((2048 / 256) * (M / 256)), 512, 0, stream>>>(
        h_bf, fw1T, fb1, ffnmid, nullptr, nullptr, M, 2048, 512);
    // 7. out = x2 + ffnmid @ fw2 + fb2 (128² tile, N=512)
    gemm_mfma<0, 1, 0><<<dim3((512 / 128) * (M / 128)), 256, 0, stream>>>(
        ffnmid, fw2T, fb2, x2, out, nullptr, nullptr, M, 512, 2048);
}

// Round 9
// 499.432 us; speedup vs baseline: 1.0886x; 1.0711x over previous
//
#include <hip/hip_runtime.h>
#include <math.h>

#define BB 32
#define LL 512
#define DD 512
#define NH 8
#define HD 64

typedef __attribute__((ext_vector_type(8))) short bf16x8;
typedef __attribute__((ext_vector_type(4))) float f32x4;

__device__ __forceinline__ unsigned short f2bf(float x) {
    union { float f; unsigned u; } v; v.f = x;
    unsigned r = v.u + 0x7fffu + ((v.u >> 16) & 1u);  // RNE
    return (unsigned short)(r >> 16);
}

// ---------------- reductions ----------------
__device__ __forceinline__ float warp_sum(float v) {
    #pragma unroll
    for (int o = 32; o > 0; o >>= 1) v += __shfl_down(v, o);
    return v;
}

// ---------------- LayerNorm: one block per row of 512, bf16 out ----------------
__global__ void ln_kernel(const float* __restrict__ X, const float* __restrict__ g,
                          const float* __restrict__ b, unsigned short* __restrict__ Y) {
    __shared__ float red[8];
    const size_t base = (size_t)blockIdx.x * DD;
    const int t = threadIdx.x;
    float x0 = X[base + t], x1 = X[base + t + 256];
    float s = warp_sum(x0 + x1);
    float q = warp_sum(x0 * x0 + x1 * x1);
    if ((t & 63) == 0) { red[t >> 6] = s; red[4 + (t >> 6)] = q; }
    __syncthreads();
    float S = red[0] + red[1] + red[2] + red[3];
    float Q = red[4] + red[5] + red[6] + red[7];
    float mu  = S * (1.0f / 512.0f);
    float var = Q * (1.0f / 512.0f) - mu * mu;
    float r = rsqrtf(var + 1e-5f);
    Y[base + t]       = f2bf((x0 - mu) * r * g[t] + b[t]);
    Y[base + t + 256] = f2bf((x1 - mu) * r * g[t + 256] + b[t + 256]);
}

// ---------------- merged weight transpose + bf16 cast (4 matrices, 1 launch) ----------------
// tile ranges: qkv_w(512x1536): [0,768)  out_w(512x512): [768,1024)
//              fw1(512x2048):   [1024,2048)  fw2(2048x512): [2048,3072)
__global__ void transpose_all(const float* __restrict__ qkv_w, unsigned short* __restrict__ qkv_wT,
                              const float* __restrict__ out_w, unsigned short* __restrict__ out_wT,
                              const float* __restrict__ fw1,   unsigned short* __restrict__ fw1T,
                              const float* __restrict__ fw2,   unsigned short* __restrict__ fw2T) {
    __shared__ float t[32][33];
    int bid = blockIdx.x;
    const float* W; unsigned short* WT; int K, N, tile;
    if (bid < 768)       { W = qkv_w; WT = qkv_wT; K = 512;  N = 1536; tile = bid; }
    else if (bid < 1024) { W = out_w; WT = out_wT; K = 512;  N = 512;  tile = bid - 768; }
    else if (bid < 2048) { W = fw1;   WT = fw1T;   K = 512;  N = 2048; tile = bid - 1024; }
    else                 { W = fw2;   WT = fw2T;   K = 2048; N = 512;  tile = bid - 2048; }
    const int nx = N >> 5;
    const int n0 = (tile % nx) * 32, k0 = (tile / nx) * 32;
    const int tx = threadIdx.x & 31, ty = threadIdx.x >> 5;
    #pragma unroll
    for (int r = 0; r < 32; r += 8)
        t[ty + r][tx] = W[(size_t)(k0 + ty + r) * N + n0 + tx];
    __syncthreads();
    #pragma unroll
    for (int r = 0; r < 32; r += 8)
        WT[(size_t)(n0 + ty + r) * K + k0 + tx] = f2bf(t[tx][ty + r]);
}

// ---------------- shared epilogue element-store ----------------
// OM: 0 = f32 out, 1 = bf16 out,
//     2 = qkv split: Q (x0.125 folded) -> row-major [row][512]; K/V -> frag blobs.
template <int ACT, int RES, int OM>
__device__ __forceinline__ void epi_store(
    float v, int row, int col, int N,
    const float* __restrict__ res, void* __restrict__ Cv,
    unsigned short* __restrict__ kfrag, unsigned short* __restrict__ vfrag) {
    if (ACT == 1) v = 0.5f * v * (1.0f + erff(v * 0.70710678118654752f));
    if (RES) v += res[(size_t)row * N + col];
    if (OM == 0) {
        ((float*)Cv)[(size_t)row * N + col] = v;
    } else if (OM == 1) {
        ((unsigned short*)Cv)[(size_t)row * N + col] = f2bf(v);
    } else {
        const int b = row >> 9, kpos = row & 511;
        if (col < 512) {
            // Q: fold the 1/sqrt(HD)=0.125 score scale here (exact, exponent-only)
            ((unsigned short*)Cv)[(size_t)row * 512 + col] = f2bf(v * 0.125f);
        } else if (col < 1024) {
            const int h = (col - 512) >> 6, dd = (col - 512) & 63;
            const int kt = kpos >> 6, jj = (kpos >> 4) & 3, lo2 = kpos & 15;
            const int kk = dd >> 5, hi2 = (dd >> 3) & 3, e = dd & 7;
            kfrag[((((size_t)(b * NH + h) * 8 + kt) * 2 + kk) * 4 + jj) * 512
                  + (hi2 * 16 + lo2) * 8 + e] = f2bf(v);
        } else {
            const int h = (col - 1024) >> 6, dd = (col - 1024) & 63;
            const int kt = kpos >> 6, kk = (kpos >> 5) & 1, hi2 = (kpos >> 3) & 3, e = kpos & 7;
            const int jj = dd >> 4, lo2 = dd & 15;
            vfrag[((((size_t)(b * NH + h) * 8 + kt) * 2 + kk) * 4 + jj) * 512
                  + (hi2 * 16 + lo2) * 8 + e] = f2bf(v);
        }
    }
}

// ---------------- bf16 MFMA GEMM, 128x128 tile, 2-phase staging (R6 keeper) ----------------
// 2-phase (T3-minimal): two STATIC LDS buffer pairs, one barrier per K-step;
// stage of tile t+1 issued BEFORE compute(t), drains at the NEXT barrier.
// 64 KB LDS -> 2 blocks/CU (cross-block TLP covers residual drain).
// Grid 1D with XCD-bijective chunked swizzle (T1). 256² at 1 block/CU
// regressed (R8: no TLP + partial-chip rounds) -> 128² is the keeper.
template <int ACT, int RES, int OM>
__global__ __launch_bounds__(256)
void gemm_mfma(const unsigned short* __restrict__ A, const unsigned short* __restrict__ BT,
               const float* __restrict__ bias, const float* __restrict__ res,
               void* __restrict__ Cv, unsigned short* __restrict__ kfrag,
               unsigned short* __restrict__ vfrag, int M, int N, int K) {
    __shared__ unsigned short As0[128 * 64];
    __shared__ unsigned short Bs0[128 * 64];
    __shared__ unsigned short As1[128 * 64];
    __shared__ unsigned short Bs1[128 * 64];
    const int tid = threadIdx.x;
    const int wave = tid >> 6, lane = tid & 63;
    const int wm = (wave >> 1) * 64, wn = (wave & 1) * 64;

    // XCD-bijective chunked swizzle (all grids %8==0)
    const int nx = N >> 7;
    const int chunk = (int)gridDim.x >> 3;
    const int o = ((int)blockIdx.x & 7) * chunk + ((int)blockIdx.x >> 3);
    const int bn = (o % nx) * 128;
    const int bm = (o / nx) * 128;

    f32x4 acc[4][4] = {};

    auto stage = [&](unsigned short* AS, unsigned short* BS, int k0) {
        #pragma unroll
        for (int it = 0; it < 4; ++it) {
            const int s = it * 256 + tid;
            const int row = s >> 3, pch = s & 7;
            const int lch = pch ^ (row & 7);
            const unsigned short* ga = A + (size_t)(bm + row) * K + k0 + lch * 8;
            __builtin_amdgcn_global_load_lds(
                (const __attribute__((address_space(1))) void*)ga,
                (__attribute__((address_space(3))) void*)(AS + s * 8), 16, 0, 0);
            const unsigned short* gb = BT + (size_t)(bn + row) * K + k0 + lch * 8;
            __builtin_amdgcn_global_load_lds(
                (const __attribute__((address_space(1))) void*)gb,
                (__attribute__((address_space(3))) void*)(BS + s * 8), 16, 0, 0);
        }
    };

    auto compute = [&](const unsigned short* AS, const unsigned short* BS) {
        #pragma unroll
        for (int ks = 0; ks < 2; ++ks) {
            bf16x8 af[4], bfr[4];
            #pragma unroll
            for (int i = 0; i < 4; ++i) {
                const int row = wm + i * 16 + (lane & 15);
                const int pch = (ks * 4 + (lane >> 4)) ^ (row & 7);
                af[i] = *(const bf16x8*)(AS + row * 64 + pch * 8);
            }
            #pragma unroll
            for (int j = 0; j < 4; ++j) {
                const int row = wn + j * 16 + (lane & 15);
                const int pch = (ks * 4 + (lane >> 4)) ^ (row & 7);
                bfr[j] = *(const bf16x8*)(BS + row * 64 + pch * 8);
            }
            #pragma unroll
            for (int i = 0; i < 4; ++i)
                #pragma unroll
                for (int j = 0; j < 4; ++j)
                    acc[i][j] = __builtin_amdgcn_mfma_f32_16x16x32_bf16(
                        af[i], bfr[j], acc[i][j], 0, 0, 0);
        }
    };

    stage(As0, Bs0, 0);
    for (int k0 = 0; k0 < K; k0 += 128) {
        __syncthreads();
        if (k0 + 64 < K) stage(As1, Bs1, k0 + 64);
        compute(As0, Bs0);
        __syncthreads();
        if (k0 + 128 < K) stage(As0, Bs0, k0 + 128);
        compute(As1, Bs1);
    }

    const int cl = lane & 15, rq = (lane >> 4) * 4;
    #pragma unroll
    for (int j = 0; j < 4; ++j) {
        const int col = bn + wn + j * 16 + cl;
        const float bv = bias[col];
        #pragma unroll
        for (int i = 0; i < 4; ++i) {
            const int r0 = bm + wm + i * 16 + rq;
            #pragma unroll
            for (int r = 0; r < 4; ++r)
                epi_store<ACT, RES, OM>(acc[i][j][r] + bv, r0 + r, col, N, res, Cv, kfrag, vfrag);
        }
    }
}

// ---------------- fused flash attention (v4 keeper + defer-max) ----------------
// grid: (qg=32, b=32), 512 threads = 8 waves; wave w = head w.
// Schedule: barrier -> kf -> vf -> stage(kt+1) -> QK^T -> bias -> softmax ->
// P-LDS -> PV. VGPR must stay <= 64 (R7: 84 VGPR -> occupancy 23%, 102->127us).
// NEW (T13 defer-max, isolated this time): the alpha-rescale path holds the
// longest SERIAL segment of the softmax chain (4 dependent broadcast shuffles
// ~50cy each + 16 v_mul on o + lsum mul). Skip it when __all(mx - m <= 8):
// true for nearly all tiles after the first, P <= e^8 safe in bf16. lsum
// scales by the lane's own alpha (no shuffle); broadcasts only in the branch.
__global__ __launch_bounds__(512)
void flash_kernel(const unsigned short* __restrict__ qbuf,
                  const unsigned short* __restrict__ kfrag,
                  const unsigned short* __restrict__ vfrag,
                  const float* __restrict__ inter,
                  const float* __restrict__ iw,
                  unsigned short* __restrict__ O) {
    __shared__ float it[2][16 * 256];               // 2 x 16 KB inter tiles (linear)
    __shared__ unsigned short plds[8][16 * 72];     // per-wave P tile
    const int qg = blockIdx.x, b = blockIdx.y;
    const int tid = threadIdx.x, wave = tid >> 6, lane = tid & 63;
    const int h = wave;
    const int lo = lane & 15, hi = lane >> 4;

    const float iw0 = iw[h], iw1 = iw[8 + h], iw2 = iw[16 + h], iw3 = iw[24 + h];
    const float* interb = inter + (size_t)b * 512 * 512 * 4;
    unsigned short* pw = &plds[wave][0];

    // Q fragment (pre-scaled 0.125): q-row = lo, d = kk*32 + hi*8 + e
    const unsigned short* qp = qbuf + ((size_t)(b * 512 + qg * 16 + lo)) * 512 + h * 64 + hi * 8;
    const bf16x8 qf0 = *(const bf16x8*)(qp);
    const bf16x8 qf1 = *(const bf16x8*)(qp + 32);

    // fragment blob bases (kt stride = 2*4*512 u16 = 4096)
    const unsigned short* kfb = kfrag + (size_t)(b * NH + h) * 32768 + (size_t)lane * 8;
    const unsigned short* vfb = vfrag + (size_t)(b * NH + h) * 32768 + (size_t)lane * 8;

    // staging: wave w stages tile rows {2w, 2w+1}; LDS dest linear,
    // global source chunk XOR-swizzled (lane ^ (row&7)).
    const int srow0 = wave * 2, srow1 = wave * 2 + 1;
    const float* sg0 = interb + (((size_t)(qg * 16 + srow0)) * 512 + (lane ^ (srow0 & 7))) * 4;
    const float* sg1 = interb + (((size_t)(qg * 16 + srow1)) * 512 + (lane ^ (srow1 & 7))) * 4;

    f32x4 o[4] = {};
    float m = -1e30f, lsum = 0.0f;

    // prologue: stage tile 0 into it[0]
    __builtin_amdgcn_global_load_lds(
        (const __attribute__((address_space(1))) void*)sg0,
        (__attribute__((address_space(3))) void*)(&it[0][srow0 * 256] + lane * 4), 16, 0, 0);
    __builtin_amdgcn_global_load_lds(
        (const __attribute__((address_space(1))) void*)sg1,
        (__attribute__((address_space(3))) void*)(&it[0][srow1 * 256] + lane * 4), 16, 0, 0);

    #pragma unroll 1
    for (int kt = 0; kt < 8; ++kt) {
        const int buf = kt & 1;
        __syncthreads();  // it[buf] staged & visible; it[buf^1] free to overwrite
        // (1) K fragments (oldest in vmcnt queue -> counted wait at QK^T)
        const unsigned short* kp = kfb + kt * 4096;
        bf16x8 kf[8];
        #pragma unroll
        for (int jj = 0; jj < 8; ++jj)
            kf[jj] = *(const bf16x8*)(kp + jj * 512);
        // (2) V fragments (consumed at PV; older than stage so PV's wait
        //     never forces the HBM stage to complete)
        const unsigned short* vp = vfb + kt * 4096;
        bf16x8 vf[8];
        #pragma unroll
        for (int jj = 0; jj < 8; ++jj)
            vf[jj] = *(const bf16x8*)(vp + jj * 512);
        // (3) stage tile kt+1 (youngest; drains at next barrier)
        if (kt < 7) {
            const int kb2 = (kt + 1) * 64;
            __builtin_amdgcn_global_load_lds(
                (const __attribute__((address_space(1))) void*)(sg0 + kb2 * 4),
                (__attribute__((address_space(3))) void*)(&it[buf ^ 1][srow0 * 256] + lane * 4),
                16, 0, 0);
            __builtin_amdgcn_global_load_lds(
                (const __attribute__((address_space(1))) void*)(sg1 + kb2 * 4),
                (__attribute__((address_space(3))) void*)(&it[buf ^ 1][srow1 * 256] + lane * 4),
                16, 0, 0);
        }
        __builtin_amdgcn_sched_barrier(0);
        // (4) S^T = K Q^T : lane owns q = lo, k = j*16 + hi*4 + r
        f32x4 s4[4] = {};
        __builtin_amdgcn_s_setprio(1);
        #pragma unroll
        for (int j = 0; j < 4; ++j)
            s4[j] = __builtin_amdgcn_mfma_f32_16x16x32_bf16(kf[j], qf0, s4[j], 0, 0, 0);
        #pragma unroll
        for (int j = 0; j < 4; ++j)
            s4[j] = __builtin_amdgcn_mfma_f32_16x16x32_bf16(kf[4 + j], qf1, s4[j], 0, 0, 0);
        __builtin_amdgcn_s_setprio(0);
        // (5) bias from LDS (swizzled read: chunk c stored at c^(lo&7)); Q pre-scaled
        {
            const float* bb = &it[buf][lo * 256];
            const int x7 = lo & 7;
            #pragma unroll
            for (int j = 0; j < 4; ++j) {
                #pragma unroll
                for (int r = 0; r < 4; ++r) {
                    const int c = (((hi * 4 + r) ^ x7) + j * 16) * 4;
                    const float4 f = *(const float4*)(bb + c);
                    s4[j][r] = s4[j][r] + f.x * iw0 + f.y * iw1 + f.z * iw2 + f.w * iw3;
                }
            }
        }
        // (6) online softmax with defer-max; per-lane row q = lo
        float t0 = fmaxf(fmaxf(s4[0][0], s4[0][1]), fmaxf(s4[0][2], s4[0][3]));
        float t1 = fmaxf(fmaxf(s4[1][0], s4[1][1]), fmaxf(s4[1][2], s4[1][3]));
        float t2 = fmaxf(fmaxf(s4[2][0], s4[2][1]), fmaxf(s4[2][2], s4[2][3]));
        float t3 = fmaxf(fmaxf(s4[3][0], s4[3][1]), fmaxf(s4[3][2], s4[3][3]));
        float mx = fmaxf(fmaxf(t0, t1), fmaxf(t2, t3));
        mx = fmaxf(mx, __shfl_xor(mx, 16));
        mx = fmaxf(mx, __shfl_xor(mx, 32));
        if (!__all((mx - m) <= 8.0f)) {             // rare: max grew materially
            const float mn = fmaxf(m, mx);
            const float al = __expf(m - mn);
            m = mn;
            lsum *= al;                             // lane's own row: no shuffle
            const float aR0 = __shfl(al, hi * 4 + 0);
            const float aR1 = __shfl(al, hi * 4 + 1);
            const float aR2 = __shfl(al, hi * 4 + 2);
            const float aR3 = __shfl(al, hi * 4 + 3);
            #pragma unroll
            for (int j2 = 0; j2 < 4; ++j2) {
                o[j2][0] *= aR0; o[j2][1] *= aR1; o[j2][2] *= aR2; o[j2][3] *= aR3;
            }
        }
        #pragma unroll
        for (int j = 0; j < 4; ++j)
            #pragma unroll
            for (int r = 0; r < 4; ++r)
                s4[j][r] = __expf(s4[j][r] - m);    // bounded by e^8 when deferred
        float u0 = (s4[0][0] + s4[0][1]) + (s4[0][2] + s4[0][3]);
        float u1 = (s4[1][0] + s4[1][1]) + (s4[1][2] + s4[1][3]);
        float u2 = (s4[2][0] + s4[2][1]) + (s4[2][2] + s4[2][3]);
        float u3 = (s4[3][0] + s4[3][1]) + (s4[3][2] + s4[3][3]);
        float ts = (u0 + u1) + (u2 + u3);
        ts += __shfl_xor(ts, 16);
        ts += __shfl_xor(ts, 32);
        lsum += ts;
        // (7) P -> LDS, packed b64, wave-private (no barrier needed)
        uint2* pq = (uint2*)(pw + lo * 72);
        #pragma unroll
        for (int j = 0; j < 4; ++j) {
            uint2 d;
            d.x = (unsigned)f2bf(s4[j][0]) | ((unsigned)f2bf(s4[j][1]) << 16);
            d.y = (unsigned)f2bf(s4[j][2]) | ((unsigned)f2bf(s4[j][3]) << 16);
            pq[j * 4 + hi] = d;
        }
        // (8) O += P V
        __builtin_amdgcn_s_setprio(1);
        #pragma unroll
        for (int kk = 0; kk < 2; ++kk) {
            const bf16x8 pf = *(const bf16x8*)(pw + lo * 72 + kk * 32 + hi * 8);
            #pragma unroll
            for (int j2 = 0; j2 < 4; ++j2)
                o[j2] = __builtin_amdgcn_mfma_f32_16x16x32_bf16(
                    pf, vf[kk * 4 + j2], o[j2], 0, 0, 0);
        }
        __builtin_amdgcn_s_setprio(0);
    }

    // ---- epilogue ----
    const float iR0 = 1.0f / __shfl(lsum, hi * 4 + 0);
    const float iR1 = 1.0f / __shfl(lsum, hi * 4 + 1);
    const float iR2 = 1.0f / __shfl(lsum, hi * 4 + 2);
    const float iR3 = 1.0f / __shfl(lsum, hi * 4 + 3);
    const int qC0 = qg * 16 + hi * 4;
    #pragma unroll
    for (int j2 = 0; j2 < 4; ++j2) {
        O[(size_t)(b * 512 + qC0 + 0) * 512 + h * 64 + j2 * 16 + lo] = f2bf(o[j2][0] * iR0);
        O[(size_t)(b * 512 + qC0 + 1) * 512 + h * 64 + j2 * 16 + lo] = f2bf(o[j2][1] * iR1);
        O[(size_t)(b * 512 + qC0 + 2) * 512 + h * 64 + j2 * 16 + lo] = f2bf(o[j2][2] * iR2);
        O[(size_t)(b * 512 + qC0 + 3) * 512 + h * 64 + j2 * 16 + lo] = f2bf(o[j2][3] * iR3);
    }
}

// ---------------- launch ----------------
extern "C" void kernel_launch(void* const* d_in, const int* in_sizes, int n_in,
                              void* d_out, int out_size, void* d_ws, size_t ws_size,
                              hipStream_t stream) {
    const float* x     = (const float*)d_in[0];
    const float* inter = (const float*)d_in[1];
    const float* qkv_w = (const float*)d_in[2];
    const float* qkv_b = (const float*)d_in[3];
    const float* out_w = (const float*)d_in[4];
    const float* out_b = (const float*)d_in[5];
    const float* n1g   = (const float*)d_in[6];
    const float* n1b   = (const float*)d_in[7];
    const float* n2g   = (const float*)d_in[8];
    const float* n2b   = (const float*)d_in[9];
    const float* iw    = (const float*)d_in[10];
    const float* fw1   = (const float*)d_in[11];
    const float* fb1   = (const float*)d_in[12];
    const float* fw2   = (const float*)d_in[13];
    const float* fb2   = (const float*)d_in[14];
    float* out = (float*)d_out;

    // workspace layout (bytes): total 190,840,832
    //   qbuf    @ 0           : 16,777,216  (16384 x 512 bf16 Q, pre-scaled 0.125)
    //   kfrag   @ 16777216    : 16,777,216  (fragment blobs)
    //   vfrag   @ 33554432    : 16,777,216  (fragment blobs)
    //   attnout @ 50331648    : 16,777,216
    //   x2      @ 67108864    : 33,554,432  (fp32)
    //   h_bf    @ 100663296   : 16,777,216
    //   ffnmid  @ 117440512   : 67,108,864
    //   weights @ 184549376   : ~6.3 MB
    if (ws_size < 190840832ull) return;
    char* ws = (char*)d_ws;
    unsigned short* qbuf    = (unsigned short*)(ws);
    unsigned short* kfrag   = (unsigned short*)(ws + 16777216ull);
    unsigned short* vfrag   = (unsigned short*)(ws + 33554432ull);
    unsigned short* attnout = (unsigned short*)(ws + 50331648ull);
    float*          x2      = (float*)(ws + 67108864ull);
    unsigned short* h_bf    = (unsigned short*)(ws + 100663296ull);
    unsigned short* ffnmid  = (unsigned short*)(ws + 117440512ull);
    unsigned short* qkv_wT  = (unsigned short*)(ws + 184549376ull);
    unsigned short* out_wT  = (unsigned short*)(ws + 186122240ull);
    unsigned short* fw1T    = (unsigned short*)(ws + 186646528ull);
    unsigned short* fw2T    = (unsigned short*)(ws + 188743680ull);

    const int M = BB * LL;  // 16384

    // 0. all weight transposes in ONE launch (3072 tiles)
    transpose_all<<<dim3(3072), 256, 0, stream>>>(qkv_w, qkv_wT, out_w, out_wT,
                                                  fw1, fw1T, fw2, fw2T);
    // 1. LN1: x -> h_bf
    ln_kernel<<<M, 256, 0, stream>>>(x, n1g, n1b, h_bf);
    // 2. qkv GEMM (128², 2-phase) -> qbuf + kfrag + vfrag; 1D swizzled grid
    gemm_mfma<0, 0, 2><<<dim3((1536 / 128) * (M / 128)), 256, 0, stream>>>(
        h_bf, qkv_wT, qkv_b, nullptr, qbuf, kfrag, vfrag, M, 1536, 512);
    // 3. fused flash attention (v4 keeper + defer-max)
    flash_kernel<<<dim3(LL / 16, BB), 512, 0, stream>>>(qbuf, kfrag, vfrag, inter, iw, attnout);
    // 4. x2 = x + attnout @ out_w + out_b
    gemm_mfma<0, 1, 0><<<dim3((512 / 128) * (M / 128)), 256, 0, stream>>>(
        attnout, out_wT, out_b, x, x2, nullptr, nullptr, M, 512, 512);
    // 5. LN2: x2 -> h_bf
    ln_kernel<<<M, 256, 0, stream>>>(x2, n2g, n2b, h_bf);
    // 6. ffnmid = gelu(h2 @ fw1 + fb1) -> bf16
    gemm_mfma<1, 0, 1><<<dim3((2048 / 128) * (M / 128)), 256, 0, stream>>>(
        h_bf, fw1T, fb1, nullptr, ffnmid, nullptr, nullptr, M, 2048, 512);
    // 7. out = x2 + ffnmid @ fw2 + fb2
    gemm_mfma<0, 1, 0><<<dim3((512 / 128) * (M / 128)), 256, 0, stream>>>(
        ffnmid, fw2T, fb2, x2, out, nullptr, nullptr, M, 512, 2048);
}

// Round 10
// 479.700 us; speedup vs baseline: 1.1333x; 1.0411x over previous
//
#include <hip/hip_runtime.h>
#include <math.h>

#define BB 32
#define LL 512
#define DD 512
#define NH 8
#define HD 64

typedef __attribute__((ext_vector_type(8))) short bf16x8;
typedef __attribute__((ext_vector_type(4))) float f32x4;

__device__ __forceinline__ unsigned short f2bf(float x) {
    union { float f; unsigned u; } v; v.f = x;
    unsigned r = v.u + 0x7fffu + ((v.u >> 16) & 1u);  // RNE
    return (unsigned short)(r >> 16);
}

// ---------------- reductions ----------------
__device__ __forceinline__ float warp_sum(float v) {
    #pragma unroll
    for (int o = 32; o > 0; o >>= 1) v += __shfl_down(v, o);
    return v;
}

// ---------------- LayerNorm: one block per row of 512, bf16 out ----------------
__global__ void ln_kernel(const float* __restrict__ X, const float* __restrict__ g,
                          const float* __restrict__ b, unsigned short* __restrict__ Y) {
    __shared__ float red[8];
    const size_t base = (size_t)blockIdx.x * DD;
    const int t = threadIdx.x;
    float x0 = X[base + t], x1 = X[base + t + 256];
    float s = warp_sum(x0 + x1);
    float q = warp_sum(x0 * x0 + x1 * x1);
    if ((t & 63) == 0) { red[t >> 6] = s; red[4 + (t >> 6)] = q; }
    __syncthreads();
    float S = red[0] + red[1] + red[2] + red[3];
    float Q = red[4] + red[5] + red[6] + red[7];
    float mu  = S * (1.0f / 512.0f);
    float var = Q * (1.0f / 512.0f) - mu * mu;
    float r = rsqrtf(var + 1e-5f);
    Y[base + t]       = f2bf((x0 - mu) * r * g[t] + b[t]);
    Y[base + t + 256] = f2bf((x1 - mu) * r * g[t + 256] + b[t + 256]);
}

// ---------------- merged weight transpose + bf16 cast (4 matrices, 1 launch) ----------------
__global__ void transpose_all(const float* __restrict__ qkv_w, unsigned short* __restrict__ qkv_wT,
                              const float* __restrict__ out_w, unsigned short* __restrict__ out_wT,
                              const float* __restrict__ fw1,   unsigned short* __restrict__ fw1T,
                              const float* __restrict__ fw2,   unsigned short* __restrict__ fw2T) {
    __shared__ float t[32][33];
    int bid = blockIdx.x;
    const float* W; unsigned short* WT; int K, N, tile;
    if (bid < 768)       { W = qkv_w; WT = qkv_wT; K = 512;  N = 1536; tile = bid; }
    else if (bid < 1024) { W = out_w; WT = out_wT; K = 512;  N = 512;  tile = bid - 768; }
    else if (bid < 2048) { W = fw1;   WT = fw1T;   K = 512;  N = 2048; tile = bid - 1024; }
    else                 { W = fw2;   WT = fw2T;   K = 2048; N = 512;  tile = bid - 2048; }
    const int nx = N >> 5;
    const int n0 = (tile % nx) * 32, k0 = (tile / nx) * 32;
    const int tx = threadIdx.x & 31, ty = threadIdx.x >> 5;
    #pragma unroll
    for (int r = 0; r < 32; r += 8)
        t[ty + r][tx] = W[(size_t)(k0 + ty + r) * N + n0 + tx];
    __syncthreads();
    #pragma unroll
    for (int r = 0; r < 32; r += 8)
        WT[(size_t)(n0 + ty + r) * K + k0 + tx] = f2bf(t[tx][ty + r]);
}

// ---------------- shared epilogue element-store ----------------
// OM: 0 = f32 out, 1 = bf16 out,
//     2 = qkv split: Q (x0.125 folded) -> row-major [row][512]; K/V -> frag blobs.
// ACT==1: sigmoid-form tanh-GELU (~9 VALU + 1 v_exp_f32 vs erff's ~30 VALU;
// max |err| vs exact erf-GELU ~1e-3, attenuated through fw2).
template <int ACT, int RES, int OM>
__device__ __forceinline__ void epi_store(
    float v, int row, int col, int N,
    const float* __restrict__ res, void* __restrict__ Cv,
    unsigned short* __restrict__ kfrag, unsigned short* __restrict__ vfrag) {
    if (ACT == 1) {
        const float u = v * 0.7978845608f * (1.0f + 0.044715f * v * v);
        v = v / (1.0f + __expf(-2.0f * u));   // v * sigmoid(2u); overflow-safe
    }
    if (RES) v += res[(size_t)row * N + col];
    if (OM == 0) {
        ((float*)Cv)[(size_t)row * N + col] = v;
    } else if (OM == 1) {
        ((unsigned short*)Cv)[(size_t)row * N + col] = f2bf(v);
    } else {
        const int b = row >> 9, kpos = row & 511;
        if (col < 512) {
            // Q: fold the 1/sqrt(HD)=0.125 score scale here (exact, exponent-only)
            ((unsigned short*)Cv)[(size_t)row * 512 + col] = f2bf(v * 0.125f);
        } else if (col < 1024) {
            const int h = (col - 512) >> 6, dd = (col - 512) & 63;
            const int kt = kpos >> 6, jj = (kpos >> 4) & 3, lo2 = kpos & 15;
            const int kk = dd >> 5, hi2 = (dd >> 3) & 3, e = dd & 7;
            kfrag[((((size_t)(b * NH + h) * 8 + kt) * 2 + kk) * 4 + jj) * 512
                  + (hi2 * 16 + lo2) * 8 + e] = f2bf(v);
        } else {
            const int h = (col - 1024) >> 6, dd = (col - 1024) & 63;
            const int kt = kpos >> 6, kk = (kpos >> 5) & 1, hi2 = (kpos >> 3) & 3, e = kpos & 7;
            const int jj = dd >> 4, lo2 = dd & 15;
            vfrag[((((size_t)(b * NH + h) * 8 + kt) * 2 + kk) * 4 + jj) * 512
                  + (hi2 * 16 + lo2) * 8 + e] = f2bf(v);
        }
    }
}

// ---------------- bf16 MFMA GEMM, 128x128 tile, 2-phase staging (R6 keeper) ----------------
template <int ACT, int RES, int OM>
__global__ __launch_bounds__(256)
void gemm_mfma(const unsigned short* __restrict__ A, const unsigned short* __restrict__ BT,
               const float* __restrict__ bias, const float* __restrict__ res,
               void* __restrict__ Cv, unsigned short* __restrict__ kfrag,
               unsigned short* __restrict__ vfrag, int M, int N, int K) {
    __shared__ unsigned short As0[128 * 64];
    __shared__ unsigned short Bs0[128 * 64];
    __shared__ unsigned short As1[128 * 64];
    __shared__ unsigned short Bs1[128 * 64];
    const int tid = threadIdx.x;
    const int wave = tid >> 6, lane = tid & 63;
    const int wm = (wave >> 1) * 64, wn = (wave & 1) * 64;

    // XCD-bijective chunked swizzle (all grids %8==0)
    const int nx = N >> 7;
    const int chunk = (int)gridDim.x >> 3;
    const int o = ((int)blockIdx.x & 7) * chunk + ((int)blockIdx.x >> 3);
    const int bn = (o % nx) * 128;
    const int bm = (o / nx) * 128;

    f32x4 acc[4][4] = {};

    auto stage = [&](unsigned short* AS, unsigned short* BS, int k0) {
        #pragma unroll
        for (int it = 0; it < 4; ++it) {
            const int s = it * 256 + tid;
            const int row = s >> 3, pch = s & 7;
            const int lch = pch ^ (row & 7);
            const unsigned short* ga = A + (size_t)(bm + row) * K + k0 + lch * 8;
            __builtin_amdgcn_global_load_lds(
                (const __attribute__((address_space(1))) void*)ga,
                (__attribute__((address_space(3))) void*)(AS + s * 8), 16, 0, 0);
            const unsigned short* gb = BT + (size_t)(bn + row) * K + k0 + lch * 8;
            __builtin_amdgcn_global_load_lds(
                (const __attribute__((address_space(1))) void*)gb,
                (__attribute__((address_space(3))) void*)(BS + s * 8), 16, 0, 0);
        }
    };

    auto compute = [&](const unsigned short* AS, const unsigned short* BS) {
        #pragma unroll
        for (int ks = 0; ks < 2; ++ks) {
            bf16x8 af[4], bfr[4];
            #pragma unroll
            for (int i = 0; i < 4; ++i) {
                const int row = wm + i * 16 + (lane & 15);
                const int pch = (ks * 4 + (lane >> 4)) ^ (row & 7);
                af[i] = *(const bf16x8*)(AS + row * 64 + pch * 8);
            }
            #pragma unroll
            for (int j = 0; j < 4; ++j) {
                const int row = wn + j * 16 + (lane & 15);
                const int pch = (ks * 4 + (lane >> 4)) ^ (row & 7);
                bfr[j] = *(const bf16x8*)(BS + row * 64 + pch * 8);
            }
            #pragma unroll
            for (int i = 0; i < 4; ++i)
                #pragma unroll
                for (int j = 0; j < 4; ++j)
                    acc[i][j] = __builtin_amdgcn_mfma_f32_16x16x32_bf16(
                        af[i], bfr[j], acc[i][j], 0, 0, 0);
        }
    };

    stage(As0, Bs0, 0);
    for (int k0 = 0; k0 < K; k0 += 128) {
        __syncthreads();
        if (k0 + 64 < K) stage(As1, Bs1, k0 + 64);
        compute(As0, Bs0);
        __syncthreads();
        if (k0 + 128 < K) stage(As0, Bs0, k0 + 128);
        compute(As1, Bs1);
    }

    const int cl = lane & 15, rq = (lane >> 4) * 4;
    #pragma unroll
    for (int j = 0; j < 4; ++j) {
        const int col = bn + wn + j * 16 + cl;
        const float bv = bias[col];
        #pragma unroll
        for (int i = 0; i < 4; ++i) {
            const int r0 = bm + wm + i * 16 + rq;
            #pragma unroll
            for (int r = 0; r < 4; ++r)
                epi_store<ACT, RES, OM>(acc[i][j][r] + bv, r0 + r, col, N, res, Cv, kfrag, vfrag);
        }
    }
}

// ---------------- fused flash attention v9: KVBLK=32, 4 blocks/CU ----------------
// grid: (qg=32, b=32) = 1024 blocks, 512 thr = 8 waves; wave w = head w.
// v9 rationale: R9 counters showed occupancy 38% = a 1-block/CU TAIL: LDS
// 50 KB -> 3 blocks/CU, 1024 = 4x256, so the last 256 blocks run solo (~1/3
// of flash time, TLP-starved). Halving the K-tile (KVBLK 64->32) shrinks
// LDS to 26.6 KB (it 16 KB + plds 10 KB) -> 4 blocks/CU, EXACT residency,
// zero tail. 16 iterations, same total MFMA/exp; per-iter loads halve
// (4 kf + 4 vf + 1 gll/wave); fewer live regs -> VGPR stays <= 64 (the
// proven cliff: R7's 84 VGPR cost 25%). Frag blob sub-indexing: kpos bit 5
// = jj-high for K, = kk for V (matches epi_store packing).
__global__ __launch_bounds__(512)
void flash_kernel(const unsigned short* __restrict__ qbuf,
                  const unsigned short* __restrict__ kfrag,
                  const unsigned short* __restrict__ vfrag,
                  const float* __restrict__ inter,
                  const float* __restrict__ iw,
                  unsigned short* __restrict__ O) {
    __shared__ float it[2][16 * 128];               // 2 x 8 KB inter tiles (32 k-cols)
    __shared__ unsigned short plds[8][16 * 40];     // per-wave P tile, stride 40 u16 = 80 B
    const int qg = blockIdx.x, b = blockIdx.y;
    const int tid = threadIdx.x, wave = tid >> 6, lane = tid & 63;
    const int h = wave;
    const int lo = lane & 15, hi = lane >> 4;

    const float iw0 = iw[h], iw1 = iw[8 + h], iw2 = iw[16 + h], iw3 = iw[24 + h];
    const float* interb = inter + (size_t)b * 512 * 512 * 4;
    unsigned short* pw = &plds[wave][0];

    // Q fragment (pre-scaled 0.125): q-row = lo, d = kk*32 + hi*8 + e
    const unsigned short* qp = qbuf + ((size_t)(b * 512 + qg * 16 + lo)) * 512 + h * 64 + hi * 8;
    const bf16x8 qf0 = *(const bf16x8*)(qp);
    const bf16x8 qf1 = *(const bf16x8*)(qp + 32);

    // fragment blob bases (kt64 stride = 4096 u16)
    const unsigned short* kfb = kfrag + (size_t)(b * NH + h) * 32768 + (size_t)lane * 8;
    const unsigned short* vfb = vfrag + (size_t)(b * NH + h) * 32768 + (size_t)lane * 8;

    // staging: ONE gll per wave per iter. lane covers (row = 2w + lane>>5,
    // chunk = lane&31); LDS dest lane-linear; source chunk XOR-swizzled.
    const int srow = wave * 2 + (lane >> 5);
    const int sc = (lane & 31) ^ (srow & 7);
    const float* sgb = interb + ((size_t)(qg * 16 + srow) * 512 + sc) * 4;

    f32x4 o[4] = {};
    float m = -1e30f, lsum = 0.0f;

    // prologue: stage k-tile 0 into it[0]
    __builtin_amdgcn_global_load_lds(
        (const __attribute__((address_space(1))) void*)sgb,
        (__attribute__((address_space(3))) void*)(&it[0][wave * 2 * 128] + lane * 4), 16, 0, 0);

    #pragma unroll 1
    for (int kt = 0; kt < 16; ++kt) {
        const int buf = kt & 1;
        __syncthreads();  // it[buf] staged & visible; it[buf^1] free to overwrite
        // (1) K fragments: 4 x 1KB. k-local = j2*16 + lo, d = kk*32 + hi*8 + e
        const unsigned short* fb = kfb + (kt >> 1) * 4096;
        const int half = (kt & 1) * 2;
        const bf16x8 kf0 = *(const bf16x8*)(fb + (size_t)(half) * 512);
        const bf16x8 kf1 = *(const bf16x8*)(fb + (size_t)(half + 1) * 512);
        const bf16x8 kf2 = *(const bf16x8*)(fb + (size_t)(4 + half) * 512);
        const bf16x8 kf3 = *(const bf16x8*)(fb + (size_t)(4 + half + 1) * 512);
        // (2) V fragments: 4 x 1KB. d-group j2; kpos bit5 = kt&1
        const unsigned short* vb = vfb + (kt >> 1) * 4096 + (size_t)(kt & 1) * 4 * 512;
        bf16x8 vf[4];
        #pragma unroll
        for (int j2 = 0; j2 < 4; ++j2)
            vf[j2] = *(const bf16x8*)(vb + (size_t)j2 * 512);
        // (3) stage k-tile kt+1 (youngest; drains at next barrier)
        if (kt < 15) {
            __builtin_amdgcn_global_load_lds(
                (const __attribute__((address_space(1))) void*)(sgb + (kt + 1) * 128),
                (__attribute__((address_space(3))) void*)(&it[buf ^ 1][wave * 2 * 128] + lane * 4),
                16, 0, 0);
        }
        __builtin_amdgcn_sched_barrier(0);
        // (4) S^T = K Q^T : lane owns q = lo, k = j2*16 + hi*4 + r
        f32x4 s0 = {}, s1 = {};
        __builtin_amdgcn_s_setprio(1);
        s0 = __builtin_amdgcn_mfma_f32_16x16x32_bf16(kf0, qf0, s0, 0, 0, 0);
        s1 = __builtin_amdgcn_mfma_f32_16x16x32_bf16(kf1, qf0, s1, 0, 0, 0);
        s0 = __builtin_amdgcn_mfma_f32_16x16x32_bf16(kf2, qf1, s0, 0, 0, 0);
        s1 = __builtin_amdgcn_mfma_f32_16x16x32_bf16(kf3, qf1, s1, 0, 0, 0);
        __builtin_amdgcn_s_setprio(0);
        // (5) bias from LDS (chunk g stored at g^(row&7)); Q pre-scaled
        {
            const float* bb = &it[buf][lo * 128];
            const int x7 = lo & 7;
            #pragma unroll
            for (int r = 0; r < 4; ++r) {
                const int c = (hi * 4 + r) ^ x7;
                const float4 f = *(const float4*)(bb + c * 4);
                s0[r] = s0[r] + f.x * iw0 + f.y * iw1 + f.z * iw2 + f.w * iw3;
            }
            #pragma unroll
            for (int r = 0; r < 4; ++r) {
                const int c = (16 + hi * 4 + r) ^ x7;
                const float4 f = *(const float4*)(bb + c * 4);
                s1[r] = s1[r] + f.x * iw0 + f.y * iw1 + f.z * iw2 + f.w * iw3;
            }
        }
        // (6) online softmax with defer-max; per-lane row q = lo
        float t0 = fmaxf(fmaxf(s0[0], s0[1]), fmaxf(s0[2], s0[3]));
        float t1 = fmaxf(fmaxf(s1[0], s1[1]), fmaxf(s1[2], s1[3]));
        float mx = fmaxf(t0, t1);
        mx = fmaxf(mx, __shfl_xor(mx, 16));
        mx = fmaxf(mx, __shfl_xor(mx, 32));
        if (!__all((mx - m) <= 8.0f)) {             // rare: max grew materially
            const float mn = fmaxf(m, mx);
            const float al = __expf(m - mn);
            m = mn;
            lsum *= al;
            const float aR0 = __shfl(al, hi * 4 + 0);
            const float aR1 = __shfl(al, hi * 4 + 1);
            const float aR2 = __shfl(al, hi * 4 + 2);
            const float aR3 = __shfl(al, hi * 4 + 3);
            #pragma unroll
            for (int j2 = 0; j2 < 4; ++j2) {
                o[j2][0] *= aR0; o[j2][1] *= aR1; o[j2][2] *= aR2; o[j2][3] *= aR3;
            }
        }
        #pragma unroll
        for (int r = 0; r < 4; ++r) s0[r] = __expf(s0[r] - m);
        #pragma unroll
        for (int r = 0; r < 4; ++r) s1[r] = __expf(s1[r] - m);
        float ts = ((s0[0] + s0[1]) + (s0[2] + s0[3])) + ((s1[0] + s1[1]) + (s1[2] + s1[3]));
        ts += __shfl_xor(ts, 16);
        ts += __shfl_xor(ts, 32);
        lsum += ts;
        // (7) P -> LDS, packed b64, wave-private (no barrier needed)
        {
            uint2* pq = (uint2*)(pw + lo * 40);
            uint2 d;
            d.x = (unsigned)f2bf(s0[0]) | ((unsigned)f2bf(s0[1]) << 16);
            d.y = (unsigned)f2bf(s0[2]) | ((unsigned)f2bf(s0[3]) << 16);
            pq[hi] = d;
            d.x = (unsigned)f2bf(s1[0]) | ((unsigned)f2bf(s1[1]) << 16);
            d.y = (unsigned)f2bf(s1[2]) | ((unsigned)f2bf(s1[3]) << 16);
            pq[4 + hi] = d;
        }
        // (8) O += P V : one pf read (P[lo][hi*8+e]), 4 MFMA
        const bf16x8 pf = *(const bf16x8*)(pw + lo * 40 + hi * 8);
        __builtin_amdgcn_s_setprio(1);
        #pragma unroll
        for (int j2 = 0; j2 < 4; ++j2)
            o[j2] = __builtin_amdgcn_mfma_f32_16x16x32_bf16(pf, vf[j2], o[j2], 0, 0, 0);
        __builtin_amdgcn_s_setprio(0);
    }

    // ---- epilogue ----
    const float iR0 = 1.0f / __shfl(lsum, hi * 4 + 0);
    const float iR1 = 1.0f / __shfl(lsum, hi * 4 + 1);
    const float iR2 = 1.0f / __shfl(lsum, hi * 4 + 2);
    const float iR3 = 1.0f / __shfl(lsum, hi * 4 + 3);
    const int qC0 = qg * 16 + hi * 4;
    #pragma unroll
    for (int j2 = 0; j2 < 4; ++j2) {
        O[(size_t)(b * 512 + qC0 + 0) * 512 + h * 64 + j2 * 16 + lo] = f2bf(o[j2][0] * iR0);
        O[(size_t)(b * 512 + qC0 + 1) * 512 + h * 64 + j2 * 16 + lo] = f2bf(o[j2][1] * iR1);
        O[(size_t)(b * 512 + qC0 + 2) * 512 + h * 64 + j2 * 16 + lo] = f2bf(o[j2][2] * iR2);
        O[(size_t)(b * 512 + qC0 + 3) * 512 + h * 64 + j2 * 16 + lo] = f2bf(o[j2][3] * iR3);
    }
}

// ---------------- launch ----------------
extern "C" void kernel_launch(void* const* d_in, const int* in_sizes, int n_in,
                              void* d_out, int out_size, void* d_ws, size_t ws_size,
                              hipStream_t stream) {
    const float* x     = (const float*)d_in[0];
    const float* inter = (const float*)d_in[1];
    const float* qkv_w = (const float*)d_in[2];
    const float* qkv_b = (const float*)d_in[3];
    const float* out_w = (const float*)d_in[4];
    const float* out_b = (const float*)d_in[5];
    const float* n1g   = (const float*)d_in[6];
    const float* n1b   = (const float*)d_in[7];
    const float* n2g   = (const float*)d_in[8];
    const float* n2b   = (const float*)d_in[9];
    const float* iw    = (const float*)d_in[10];
    const float* fw1   = (const float*)d_in[11];
    const float* fb1   = (const float*)d_in[12];
    const float* fw2   = (const float*)d_in[13];
    const float* fb2   = (const float*)d_in[14];
    float* out = (float*)d_out;

    // workspace layout (bytes): total 190,840,832
    //   qbuf    @ 0           : 16,777,216  (16384 x 512 bf16 Q, pre-scaled 0.125)
    //   kfrag   @ 16777216    : 16,777,216  (fragment blobs)
    //   vfrag   @ 33554432    : 16,777,216  (fragment blobs)
    //   attnout @ 50331648    : 16,777,216
    //   x2      @ 67108864    : 33,554,432  (fp32)
    //   h_bf    @ 100663296   : 16,777,216
    //   ffnmid  @ 117440512   : 67,108,864
    //   weights @ 184549376   : ~6.3 MB
    if (ws_size < 190840832ull) return;
    char* ws = (char*)d_ws;
    unsigned short* qbuf    = (unsigned short*)(ws);
    unsigned short* kfrag   = (unsigned short*)(ws + 16777216ull);
    unsigned short* vfrag   = (unsigned short*)(ws + 33554432ull);
    unsigned short* attnout = (unsigned short*)(ws + 50331648ull);
    float*          x2      = (float*)(ws + 67108864ull);
    unsigned short* h_bf    = (unsigned short*)(ws + 100663296ull);
    unsigned short* ffnmid  = (unsigned short*)(ws + 117440512ull);
    unsigned short* qkv_wT  = (unsigned short*)(ws + 184549376ull);
    unsigned short* out_wT  = (unsigned short*)(ws + 186122240ull);
    unsigned short* fw1T    = (unsigned short*)(ws + 186646528ull);
    unsigned short* fw2T    = (unsigned short*)(ws + 188743680ull);

    const int M = BB * LL;  // 16384

    // 0. all weight transposes in ONE launch (3072 tiles)
    transpose_all<<<dim3(3072), 256, 0, stream>>>(qkv_w, qkv_wT, out_w, out_wT,
                                                  fw1, fw1T, fw2, fw2T);
    // 1. LN1: x -> h_bf
    ln_kernel<<<M, 256, 0, stream>>>(x, n1g, n1b, h_bf);
    // 2. qkv GEMM (128², 2-phase) -> qbuf + kfrag + vfrag; 1D swizzled grid
    gemm_mfma<0, 0, 2><<<dim3((1536 / 128) * (M / 128)), 256, 0, stream>>>(
        h_bf, qkv_wT, qkv_b, nullptr, qbuf, kfrag, vfrag, M, 1536, 512);
    // 3. fused flash attention (v9: KVBLK=32, 4 blocks/CU)
    flash_kernel<<<dim3(LL / 16, BB), 512, 0, stream>>>(qbuf, kfrag, vfrag, inter, iw, attnout);
    // 4. x2 = x + attnout @ out_w + out_b
    gemm_mfma<0, 1, 0><<<dim3((512 / 128) * (M / 128)), 256, 0, stream>>>(
        attnout, out_wT, out_b, x, x2, nullptr, nullptr, M, 512, 512);
    // 5. LN2: x2 -> h_bf
    ln_kernel<<<M, 256, 0, stream>>>(x2, n2g, n2b, h_bf);
    // 6. ffnmid = gelu(h2 @ fw1 + fb1) -> bf16 (fast sigmoid-GELU epilogue)
    gemm_mfma<1, 0, 1><<<dim3((2048 / 128) * (M / 128)), 256, 0, stream>>>(
        h_bf, fw1T, fb1, nullptr, ffnmid, nullptr, nullptr, M, 2048, 512);
    // 7. out = x2 + ffnmid @ fw2 + fb2
    gemm_mfma<0, 1, 0><<<dim3((512 / 128) * (M / 128)), 256, 0, stream>>>(
        ffnmid, fw2T, fb2, x2, out, nullptr, nullptr, M, 512, 2048);
}